// Round 1
// baseline (622.848 us; speedup 1.0000x reference)
//
#include <hip/hip_runtime.h>
#include <hip/hip_bf16.h>
#include <math.h>

// GRACE-style graph contrastive loss, MI355X (gfx950).
// Pipeline: batched (M=16384) bf16-MFMA GEMM chain -> CSR-gather GCN agg (fp32)
// -> normalize -> 3x streamed exp-Gram row/col sums (bf16 MFMA, fp32 acc) -> scalar loss.
// ws usage ~54 MB.

#define NROWS 8192
#define MROWS 16384
#define NEDGE 262144

typedef __attribute__((ext_vector_type(8))) short bf16x8;
typedef __attribute__((ext_vector_type(4))) float f32x4;

__device__ __forceinline__ float bf2f(short s){
  union { unsigned u; float f; } cv; cv.u = ((unsigned)(unsigned short)s) << 16; return cv.f;
}
__device__ __forceinline__ short f2bf(float f){
  union { float f; unsigned u; } cv; cv.f = f;
  unsigned u = cv.u;
  unsigned r = (u + 0x7fffu + ((u >> 16) & 1u)) >> 16;  // RNE; inputs finite
  return (short)r;
}
__device__ __forceinline__ f32x4 mfma16(bf16x8 a, bf16x8 b, f32x4 c){
  return __builtin_amdgcn_mfma_f32_16x16x32_bf16(a, b, c, 0, 0, 0);
}

// ---- weight transpose + bf16 cast: W[K,N] fp32 -> Wt[N,K] bf16 ----
__global__ void wt_k(const float* __restrict__ W, short* __restrict__ Wt, int K, int Nc){
  int i = blockIdx.x*256 + threadIdx.x;
  if (i < K*Nc){ int k = i / Nc, n = i - k*Nc; Wt[(long)n*K + k] = f2bf(W[i]); }
}

// ---- generic tall-skinny MFMA GEMM: Out[M,NN] = act(A[M,KK] @ Bt[NN,KK]^T + bias) ----
// Block = 64 rows x full NN. A/B fragments loaded straight from global (L1/L2-resident,
// grid.y==1 so A is read ~once). ACT: 0 none, 1 relu, 2 elu.
template<int NN, int KK, int ACT, bool AFP32, bool BIAS, bool OUTF32>
__global__ __launch_bounds__(256) void gemm_k(const void* __restrict__ A0, const void* __restrict__ A1,
                                              const short* __restrict__ Bt, const float* __restrict__ bias,
                                              void* __restrict__ Out){
  constexpr int WM = (NN >= 64) ? 64 : 16;
  constexpr int WN = (NN >= 64) ? (NN/4) : NN;
  constexpr int MT = WM/16, NT = WN/16;
  const int tid = threadIdx.x;
  const int wave = tid >> 6, lane = tid & 63, quad = lane >> 4, cl = lane & 15;
  const int m0 = blockIdx.x * 64;
  const int wmo = (NN >= 64) ? 0 : wave*16;
  const int wno = (NN >= 64) ? wave*WN : 0;

  f32x4 zero = {0.f,0.f,0.f,0.f};
  f32x4 acc[MT][NT];
  #pragma unroll
  for (int i=0;i<MT;i++)
    #pragma unroll
    for (int j=0;j<NT;j++) acc[i][j] = zero;

  #pragma unroll
  for (int kc = 0; kc < KK/32; kc++){
    const int ko = kc*32 + quad*8;
    bf16x8 a[MT], b[NT];
    #pragma unroll
    for (int mt=0; mt<MT; mt++){
      int row = m0 + wmo + mt*16 + cl;
      if constexpr (AFP32){
        const float* ar = (row < NROWS) ? ((const float*)A0 + (long)row*KK + ko)
                                        : ((const float*)A1 + (long)(row-NROWS)*KK + ko);
        float4 f0 = *(const float4*)ar;
        float4 f1 = *(const float4*)(ar+4);
        bf16x8 t;
        t[0]=f2bf(f0.x); t[1]=f2bf(f0.y); t[2]=f2bf(f0.z); t[3]=f2bf(f0.w);
        t[4]=f2bf(f1.x); t[5]=f2bf(f1.y); t[6]=f2bf(f1.z); t[7]=f2bf(f1.w);
        a[mt]=t;
      } else {
        a[mt] = *(const bf16x8*)((const short*)A0 + (long)row*KK + ko);
      }
    }
    #pragma unroll
    for (int nt=0; nt<NT; nt++)
      b[nt] = *(const bf16x8*)(Bt + (long)(wno + nt*16 + cl)*KK + ko);
    #pragma unroll
    for (int mt=0; mt<MT; mt++)
      #pragma unroll
      for (int nt=0; nt<NT; nt++)
        acc[mt][nt] = mfma16(a[mt], b[nt], acc[mt][nt]);
  }
  #pragma unroll
  for (int mt=0; mt<MT; mt++){
    #pragma unroll
    for (int nt=0; nt<NT; nt++){
      int col = wno + nt*16 + cl;
      float bv = 0.f;
      if constexpr (BIAS) bv = bias[col];
      #pragma unroll
      for (int r=0;r<4;r++){
        int row = m0 + wmo + mt*16 + quad*4 + r;
        float v = acc[mt][nt][r] + bv;
        if (ACT==1) v = fmaxf(v, 0.f);
        if (ACT==2) v = (v > 0.f) ? v : expm1f(v);
        if constexpr (OUTF32) ((float*)Out)[(long)row*NN + col] = v;
        else ((short*)Out)[(long)row*NN + col] = f2bf(v);
      }
    }
  }
}

// ---- CSR build ----
__global__ void hist_k(const int* __restrict__ rows, int* __restrict__ deg){
  int e = blockIdx.x*256 + threadIdx.x;
  if (e < NEDGE) atomicAdd(&deg[rows[e]], 1);
}
__global__ void scan_k(const int* __restrict__ deg, int* __restrict__ rowstart, int* __restrict__ cursor){
  __shared__ int csum[256];
  __shared__ int base[257];
  int t = threadIdx.x;
  int loc[32];
  int s = 0;
  for (int j=0;j<32;j++){ int d = deg[t*32+j]; loc[j] = s; s += d; }
  csum[t] = s;
  __syncthreads();
  if (t==0){ int a=0; for (int i=0;i<256;i++){ base[i]=a; a+=csum[i]; } base[256]=a; }
  __syncthreads();
  for (int j=0;j<32;j++){ int v = base[t] + loc[j]; rowstart[t*32+j]=v; cursor[t*32+j]=v; }
  if (t==0) rowstart[NROWS] = base[256];
}
__global__ void fill_k(const int* __restrict__ ei, const float* __restrict__ w,
                       int* __restrict__ cursor, int* __restrict__ ecol, float* __restrict__ ew){
  int e = blockIdx.x*256 + threadIdx.x;
  if (e < NEDGE){
    int r = ei[e];
    int p = atomicAdd(&cursor[r], 1);
    ecol[p] = ei[NEDGE + e];
    ew[p] = w[e];
  }
}

// ---- GCN aggregation (gather form): out[row] = act(bias + sum_e w_e * sup[col_e]) ----
// Rows 0..8191 -> graph1 / sup rows 0..; rows 8192.. -> graph2 / sup rows 8192..
template<int C, bool RELU>
__global__ __launch_bounds__(256) void gather_k(const short* __restrict__ sup,
    const int* __restrict__ rs1, const int* __restrict__ ec1, const float* __restrict__ w1,
    const int* __restrict__ rs2, const int* __restrict__ ec2, const float* __restrict__ w2,
    const float* __restrict__ bias, short* __restrict__ out){
  constexpr int CONC = 256 / C;
  constexpr int RB = 8;
  const int c = threadIdx.x % C;
  const int sub = threadIdx.x / C;
  const int b0 = blockIdx.x * RB;
  for (int rr = sub; rr < RB; rr += CONC){
    int row = b0 + rr;
    const int* rs; const int* ec; const float* w; int soff, lr;
    if (row < NROWS){ rs=rs1; ec=ec1; w=w1; soff=0; lr=row; }
    else            { rs=rs2; ec=ec2; w=w2; soff=NROWS; lr=row-NROWS; }
    float acc = bias[c];
    int s = rs[lr], e = rs[lr+1];
    for (int k=s;k<e;k++)
      acc += w[k] * bf2f(sup[(long)(soff+ec[k])*C + c]);
    if (RELU) acc = fmaxf(acc, 0.f);
    out[(long)row*C + c] = f2bf(acc);
  }
}

// ---- normalize rows of z (fp32 [16384,128]) -> bf16 z_n; also bdot[i] = z1n_i . z2n_i ----
__global__ __launch_bounds__(256) void norm_k(const float* __restrict__ z, short* __restrict__ znb,
                                              float* __restrict__ bdot){
  int wave = threadIdx.x>>6, lane = threadIdx.x&63;
  int i = blockIdx.x*4 + wave;   // 0..8191 (pair rows i and i+8192)
  const float* za = z + (long)i*128;
  const float* zb = z + (long)(i+NROWS)*128;
  float a0=za[lane], a1=za[lane+64], b0=zb[lane], b1=zb[lane+64];
  float sa = a0*a0 + a1*a1;
  float sb = b0*b0 + b1*b1;
  #pragma unroll
  for (int m=1;m<64;m<<=1){ sa += __shfl_xor(sa,m); sb += __shfl_xor(sb,m); }
  float ra = 1.f / fmaxf(sqrtf(sa), 1e-12f);
  float rb = 1.f / fmaxf(sqrtf(sb), 1e-12f);
  short* oa = znb + (long)i*128;
  short* ob = znb + (long)(i+NROWS)*128;
  oa[lane] = f2bf(a0*ra); oa[lane+64] = f2bf(a1*ra);
  ob[lane] = f2bf(b0*rb); ob[lane+64] = f2bf(b1*rb);
  float d = (a0*ra)*(b0*rb) + (a1*ra)*(b1*rb);
  #pragma unroll
  for (int m=1;m<64;m<<=1) d += __shfl_xor(d,m);
  if (lane==0) bdot[i] = d;
}

// ---- streamed exp-Gram: S = A @ B^T (128x128 tile per block, K=128, bf16 MFMA),
// rowsum += sum_j exp(2*S_ij); MODE 1: also colsum += sum_i (between matrix).
// MODE 2: symmetric (A==B): only upper-tri blocks; mirror col-sums into rowsum.
template<int MODE>
__global__ __launch_bounds__(256) void gram_k(const short* __restrict__ A, const short* __restrict__ B,
                                              float* __restrict__ rowsum, float* __restrict__ colsum){
  const int bx = blockIdx.x, by = blockIdx.y;
  if (MODE==2 && by < bx) return;
  __shared__ short As[128*136];   // +8 pad: 272B row stride, 16B aligned, 2-way-bank-free
  __shared__ short Bs[128*136];
  const int i0 = bx*128, j0 = by*128;
  const int tid = threadIdx.x;
  #pragma unroll
  for (int p=0;p<8;p++){
    int idx = p*256 + tid;
    int r = idx >> 4, cc = (idx & 15)*8;
    *(int4*)&As[r*136 + cc] = *(const int4*)(A + (long)(i0+r)*128 + cc);
    *(int4*)&Bs[r*136 + cc] = *(const int4*)(B + (long)(j0+r)*128 + cc);
  }
  __syncthreads();
  const int wave = tid>>6, lane = tid&63, quad = lane>>4, cl = lane&15;
  const int wm = (wave&1)*64, wn = (wave>>1)*64;
  f32x4 zero = {0.f,0.f,0.f,0.f};
  f32x4 acc[4][4];
  #pragma unroll
  for (int i=0;i<4;i++)
    #pragma unroll
    for (int j=0;j<4;j++) acc[i][j]=zero;
  #pragma unroll
  for (int kc=0;kc<4;kc++){
    const int ko = kc*32 + quad*8;
    bf16x8 a[4], b[4];
    #pragma unroll
    for (int mt=0;mt<4;mt++) a[mt] = *(const bf16x8*)&As[(wm+mt*16+cl)*136 + ko];
    #pragma unroll
    for (int nt=0;nt<4;nt++) b[nt] = *(const bf16x8*)&Bs[(wn+nt*16+cl)*136 + ko];
    #pragma unroll
    for (int mt=0;mt<4;mt++)
      #pragma unroll
      for (int nt=0;nt<4;nt++)
        acc[mt][nt] = mfma16(a[mt], b[nt], acc[mt][nt]);
  }
  const bool diag = (MODE==2) && (bx==by);
  float csum[4] = {0.f,0.f,0.f,0.f};
  #pragma unroll
  for (int mt=0;mt<4;mt++){
    float rs[4] = {0.f,0.f,0.f,0.f};
    #pragma unroll
    for (int nt=0;nt<4;nt++){
      f32x4 v = acc[mt][nt];
      #pragma unroll
      for (int r=0;r<4;r++){
        float e = __expf(2.f*v[r]);   // 1/TEMP = 2
        rs[r] += e;
        csum[nt] += e;
      }
    }
    #pragma unroll
    for (int r=0;r<4;r++){
      float s = rs[r];
      s += __shfl_xor(s,1); s += __shfl_xor(s,2); s += __shfl_xor(s,4); s += __shfl_xor(s,8);
      if (cl==0) atomicAdd(&rowsum[i0+wm+mt*16+quad*4+r], s);
    }
  }
  if (MODE==1 || (MODE==2 && !diag)){
    #pragma unroll
    for (int nt=0;nt<4;nt++){
      float s = csum[nt];
      s += __shfl_xor(s,16); s += __shfl_xor(s,32);
      if (quad==0){
        float* dst = (MODE==1) ? colsum : rowsum;  // symmetric: mirror into rowsum
        atomicAdd(&dst[j0+wn+nt*16+cl], s);
      }
    }
  }
}

// ---- final loss: mean_i 0.5*[ (log(d1)-2*bdot) + (log(d2)-2*bdot) ] ----
__global__ void loss_k(const float* __restrict__ r1, const float* __restrict__ r2,
                       const float* __restrict__ brow, const float* __restrict__ bcol,
                       const float* __restrict__ bdot, float* __restrict__ out){
  __shared__ float red[256];
  const float E2 = 7.3890560989306495f;  // exp(1/TEMP * 1) = diag(refl)
  int t = threadIdx.x;
  float s = 0.f;
  for (int i=t;i<NROWS;i+=256){
    float lb = 2.f * bdot[i];            // log(between_ii), fp32 exact
    float d1 = r1[i] + brow[i] - E2;
    float d2 = r2[i] + bcol[i] - E2;
    s += 0.5f * ((logf(d1) - lb) + (logf(d2) - lb));
  }
  red[t]=s; __syncthreads();
  for (int st=128; st>0; st>>=1){ if (t<st) red[t]+=red[t+st]; __syncthreads(); }
  if (t==0) out[0] = red[0] / (float)NROWS;
}

extern "C" void kernel_launch(void* const* d_in, const int* in_sizes, int n_in,
                              void* d_out, int out_size, void* d_ws, size_t ws_size,
                              hipStream_t stream){
  const float* feat1 = (const float*)d_in[0];
  const float* feat2 = (const float*)d_in[1];
  const int*   ei1   = (const int*)d_in[2];
  const float* w1    = (const float*)d_in[3];
  const int*   ei2   = (const int*)d_in[4];
  const float* w2    = (const float*)d_in[5];
  const float* w_l1a = (const float*)d_in[6];
  const float* b_l1a = (const float*)d_in[7];
  const float* w_l1b = (const float*)d_in[8];
  const float* b_l1b = (const float*)d_in[9];
  const float* w_g1  = (const float*)d_in[10];
  const float* b_g1  = (const float*)d_in[11];
  const float* w_g2  = (const float*)d_in[12];
  const float* b_g2  = (const float*)d_in[13];
  const float* w_fc1 = (const float*)d_in[14];
  const float* b_fc1 = (const float*)d_in[15];
  const float* w_fc2 = (const float*)d_in[16];
  const float* b_fc2 = (const float*)d_in[17];

  char* base = (char*)d_ws;
  size_t off = 0;
  auto alloc = [&](size_t bytes)->void*{
    void* r = base + off;
    off = (off + bytes + 255) & ~(size_t)255;
    return r;
  };
  float* z    = (float*)alloc((size_t)MROWS*128*4);
  short* znb  = (short*)alloc((size_t)MROWS*128*2);
  short* a1   = (short*)alloc((size_t)MROWS*64*2);
  short* xb   = (short*)alloc((size_t)MROWS*32*2);
  short* s1   = (short*)alloc((size_t)MROWS*256*2);
  short* hb   = (short*)alloc((size_t)MROWS*256*2);
  short* s2   = (short*)alloc((size_t)MROWS*128*2);
  short* hh   = (short*)alloc((size_t)MROWS*128*2);
  short* t2   = (short*)alloc((size_t)MROWS*64*2);
  short* wl1a_t = (short*)alloc(512*64*2);
  short* wl1b_t = (short*)alloc(64*32*2);
  short* wg1_t  = (short*)alloc(32*256*2);
  short* wg2_t  = (short*)alloc(256*128*2);
  short* wfc1_t = (short*)alloc(128*64*2);
  short* wfc2_t = (short*)alloc(64*128*2);
  // contiguous zero region: deg1 deg2 r1s r2s brow bcol (6 * 32KB, one memset)
  int*   deg1 = (int*)alloc(NROWS*4);
  int*   deg2 = (int*)alloc(NROWS*4);
  float* r1s  = (float*)alloc(NROWS*4);
  float* r2s  = (float*)alloc(NROWS*4);
  float* brow = (float*)alloc(NROWS*4);
  float* bcol = (float*)alloc(NROWS*4);
  int* rs1  = (int*)alloc((NROWS+1)*4);
  int* cur1 = (int*)alloc(NROWS*4);
  int* rs2  = (int*)alloc((NROWS+1)*4);
  int* cur2 = (int*)alloc(NROWS*4);
  int*   ecol1 = (int*)alloc((size_t)NEDGE*4);
  float* ewt1  = (float*)alloc((size_t)NEDGE*4);
  int*   ecol2 = (int*)alloc((size_t)NEDGE*4);
  float* ewt2  = (float*)alloc((size_t)NEDGE*4);
  float* bdot  = (float*)alloc(NROWS*4);

  hipMemsetAsync(deg1, 0, (size_t)6*NROWS*4, stream);

  wt_k<<<(512*64+255)/256,256,0,stream>>>(w_l1a, wl1a_t, 512, 64);
  wt_k<<<(64*32+255)/256,256,0,stream>>>(w_l1b, wl1b_t, 64, 32);
  wt_k<<<(32*256+255)/256,256,0,stream>>>(w_g1, wg1_t, 32, 256);
  wt_k<<<(256*128+255)/256,256,0,stream>>>(w_g2, wg2_t, 256, 128);
  wt_k<<<(128*64+255)/256,256,0,stream>>>(w_fc1, wfc1_t, 128, 64);
  wt_k<<<(64*128+255)/256,256,0,stream>>>(w_fc2, wfc2_t, 64, 128);

  hist_k<<<NEDGE/256,256,0,stream>>>(ei1, deg1);
  hist_k<<<NEDGE/256,256,0,stream>>>(ei2, deg2);
  scan_k<<<1,256,0,stream>>>(deg1, rs1, cur1);
  scan_k<<<1,256,0,stream>>>(deg2, rs2, cur2);
  fill_k<<<NEDGE/256,256,0,stream>>>(ei1, w1, cur1, ecol1, ewt1);
  fill_k<<<NEDGE/256,256,0,stream>>>(ei2, w2, cur2, ecol2, ewt2);

  // encoder (both graphs batched: rows 0..8191 = view1, 8192..16383 = view2)
  gemm_k<64,512,1,true,true,false><<<MROWS/64,256,0,stream>>>(feat1, feat2, wl1a_t, b_l1a, a1);
  gemm_k<32,64,0,false,true,false><<<MROWS/64,256,0,stream>>>(a1, nullptr, wl1b_t, b_l1b, xb);
  gemm_k<256,32,0,false,false,false><<<MROWS/64,256,0,stream>>>(xb, nullptr, wg1_t, nullptr, s1);
  gather_k<256,true><<<MROWS/8,256,0,stream>>>(s1, rs1,ecol1,ewt1, rs2,ecol2,ewt2, b_g1, hb);
  gemm_k<128,256,0,false,false,false><<<MROWS/64,256,0,stream>>>(hb, nullptr, wg2_t, nullptr, s2);
  gather_k<128,false><<<MROWS/8,256,0,stream>>>(s2, rs1,ecol1,ewt1, rs2,ecol2,ewt2, b_g2, hh);
  // projection
  gemm_k<64,128,2,false,true,false><<<MROWS/64,256,0,stream>>>(hh, nullptr, wfc1_t, b_fc1, t2);
  gemm_k<128,64,0,false,true,true><<<MROWS/64,256,0,stream>>>(t2, nullptr, wfc2_t, b_fc2, z);

  norm_k<<<NROWS/4,256,0,stream>>>(z, znb, bdot);

  dim3 gg(64,64);
  const short* z1b = znb;
  const short* z2b = znb + (size_t)NROWS*128;
  gram_k<2><<<gg,256,0,stream>>>(z1b, z1b, r1s, nullptr);
  gram_k<2><<<gg,256,0,stream>>>(z2b, z2b, r2s, nullptr);
  gram_k<1><<<gg,256,0,stream>>>(z1b, z2b, brow, bcol);

  loss_k<<<1,256,0,stream>>>(r1s, r2s, brow, bcol, bdot, (float*)d_out);
}

// Round 2
// 420.874 us; speedup vs baseline: 1.4799x; 1.4799x over previous
//
#include <hip/hip_runtime.h>
#include <hip/hip_bf16.h>
#include <math.h>

// GRACE-style graph contrastive loss, MI355X (gfx950).
// Pipeline: batched (M=16384) bf16-MFMA GEMM chain -> CSR-gather GCN agg (fp32)
// -> normalize -> 3x streamed exp-Gram row/col sums (bf16 MFMA, fp32 acc) -> scalar loss.
// R2: gather_k redesigned — 8-col groups, int4 gathers, 4-deep unroll for MLP
// (R1 profile: gather was latency-bound, 171us each, VALUBusy 21%, MfmaUtil 0).

#define NROWS 8192
#define MROWS 16384
#define NEDGE 262144

typedef __attribute__((ext_vector_type(8))) short bf16x8;
typedef __attribute__((ext_vector_type(4))) float f32x4;

__device__ __forceinline__ float bf2f(short s){
  union { unsigned u; float f; } cv; cv.u = ((unsigned)(unsigned short)s) << 16; return cv.f;
}
__device__ __forceinline__ short f2bf(float f){
  union { float f; unsigned u; } cv; cv.f = f;
  unsigned u = cv.u;
  unsigned r = (u + 0x7fffu + ((u >> 16) & 1u)) >> 16;  // RNE; inputs finite
  return (short)r;
}
__device__ __forceinline__ f32x4 mfma16(bf16x8 a, bf16x8 b, f32x4 c){
  return __builtin_amdgcn_mfma_f32_16x16x32_bf16(a, b, c, 0, 0, 0);
}

// ---- weight transpose + bf16 cast: W[K,N] fp32 -> Wt[N,K] bf16 ----
__global__ void wt_k(const float* __restrict__ W, short* __restrict__ Wt, int K, int Nc){
  int i = blockIdx.x*256 + threadIdx.x;
  if (i < K*Nc){ int k = i / Nc, n = i - k*Nc; Wt[(long)n*K + k] = f2bf(W[i]); }
}

// ---- generic tall-skinny MFMA GEMM: Out[M,NN] = act(A[M,KK] @ Bt[NN,KK]^T + bias) ----
template<int NN, int KK, int ACT, bool AFP32, bool BIAS, bool OUTF32>
__global__ __launch_bounds__(256) void gemm_k(const void* __restrict__ A0, const void* __restrict__ A1,
                                              const short* __restrict__ Bt, const float* __restrict__ bias,
                                              void* __restrict__ Out){
  constexpr int WM = (NN >= 64) ? 64 : 16;
  constexpr int WN = (NN >= 64) ? (NN/4) : NN;
  constexpr int MT = WM/16, NT = WN/16;
  const int tid = threadIdx.x;
  const int wave = tid >> 6, lane = tid & 63, quad = lane >> 4, cl = lane & 15;
  const int m0 = blockIdx.x * 64;
  const int wmo = (NN >= 64) ? 0 : wave*16;
  const int wno = (NN >= 64) ? wave*WN : 0;

  f32x4 zero = {0.f,0.f,0.f,0.f};
  f32x4 acc[MT][NT];
  #pragma unroll
  for (int i=0;i<MT;i++)
    #pragma unroll
    for (int j=0;j<NT;j++) acc[i][j] = zero;

  #pragma unroll
  for (int kc = 0; kc < KK/32; kc++){
    const int ko = kc*32 + quad*8;
    bf16x8 a[MT], b[NT];
    #pragma unroll
    for (int mt=0; mt<MT; mt++){
      int row = m0 + wmo + mt*16 + cl;
      if constexpr (AFP32){
        const float* ar = (row < NROWS) ? ((const float*)A0 + (long)row*KK + ko)
                                        : ((const float*)A1 + (long)(row-NROWS)*KK + ko);
        float4 f0 = *(const float4*)ar;
        float4 f1 = *(const float4*)(ar+4);
        bf16x8 t;
        t[0]=f2bf(f0.x); t[1]=f2bf(f0.y); t[2]=f2bf(f0.z); t[3]=f2bf(f0.w);
        t[4]=f2bf(f1.x); t[5]=f2bf(f1.y); t[6]=f2bf(f1.z); t[7]=f2bf(f1.w);
        a[mt]=t;
      } else {
        a[mt] = *(const bf16x8*)((const short*)A0 + (long)row*KK + ko);
      }
    }
    #pragma unroll
    for (int nt=0; nt<NT; nt++)
      b[nt] = *(const bf16x8*)(Bt + (long)(wno + nt*16 + cl)*KK + ko);
    #pragma unroll
    for (int mt=0; mt<MT; mt++)
      #pragma unroll
      for (int nt=0; nt<NT; nt++)
        acc[mt][nt] = mfma16(a[mt], b[nt], acc[mt][nt]);
  }
  #pragma unroll
  for (int mt=0; mt<MT; mt++){
    #pragma unroll
    for (int nt=0; nt<NT; nt++){
      int col = wno + nt*16 + cl;
      float bv = 0.f;
      if constexpr (BIAS) bv = bias[col];
      #pragma unroll
      for (int r=0;r<4;r++){
        int row = m0 + wmo + mt*16 + quad*4 + r;
        float v = acc[mt][nt][r] + bv;
        if (ACT==1) v = fmaxf(v, 0.f);
        if (ACT==2) v = (v > 0.f) ? v : expm1f(v);
        if constexpr (OUTF32) ((float*)Out)[(long)row*NN + col] = v;
        else ((short*)Out)[(long)row*NN + col] = f2bf(v);
      }
    }
  }
}

// ---- CSR build ----
__global__ void hist_k(const int* __restrict__ rows, int* __restrict__ deg){
  int e = blockIdx.x*256 + threadIdx.x;
  if (e < NEDGE) atomicAdd(&deg[rows[e]], 1);
}
__global__ void scan_k(const int* __restrict__ deg, int* __restrict__ rowstart, int* __restrict__ cursor){
  __shared__ int csum[256];
  __shared__ int base[257];
  int t = threadIdx.x;
  int loc[32];
  int s = 0;
  for (int j=0;j<32;j++){ int d = deg[t*32+j]; loc[j] = s; s += d; }
  csum[t] = s;
  __syncthreads();
  if (t==0){ int a=0; for (int i=0;i<256;i++){ base[i]=a; a+=csum[i]; } base[256]=a; }
  __syncthreads();
  for (int j=0;j<32;j++){ int v = base[t] + loc[j]; rowstart[t*32+j]=v; cursor[t*32+j]=v; }
  if (t==0) rowstart[NROWS] = base[256];
}
__global__ void fill_k(const int* __restrict__ ei, const float* __restrict__ w,
                       int* __restrict__ cursor, int* __restrict__ ecol, float* __restrict__ ew){
  int e = blockIdx.x*256 + threadIdx.x;
  if (e < NEDGE){
    int r = ei[e];
    int p = atomicAdd(&cursor[r], 1);
    ecol[p] = ei[NEDGE + e];
    ew[p] = w[e];
  }
}

// ---- GCN aggregation (gather form), latency-optimized ----
// Each thread owns an 8-column group of one output row; inner loop unrolled x4
// so 4 independent 16B gathers are in flight per thread.
__device__ __forceinline__ void acc8(float* acc, int4 v, float f){
  const unsigned* u = (const unsigned*)&v;
  #pragma unroll
  for (int i=0;i<4;i++){
    union{unsigned x; float y;} lo, hi;
    lo.x = u[i] << 16;
    hi.x = u[i] & 0xffff0000u;
    acc[2*i]   = fmaf(f, lo.y, acc[2*i]);
    acc[2*i+1] = fmaf(f, hi.y, acc[2*i+1]);
  }
}

template<int C, bool RELU>
__global__ __launch_bounds__(256) void gather_k(const short* __restrict__ sup,
    const int* __restrict__ rs1, const int* __restrict__ ec1, const float* __restrict__ w1,
    const int* __restrict__ rs2, const int* __restrict__ ec2, const float* __restrict__ w2,
    const float* __restrict__ bias, short* __restrict__ out){
  constexpr int G = C/8;           // 8-col groups per row: 32 (C=256) / 16 (C=128)
  constexpr int RPB = 256/G;       // rows per block: 8 / 16
  const int g = threadIdx.x % G;
  const int sub = threadIdx.x / G;
  const int row = blockIdx.x*RPB + sub;
  const int* rs; const int* ec; const float* w; int soff, lr;
  if (row < NROWS){ rs=rs1; ec=ec1; w=w1; soff=0; lr=row; }
  else            { rs=rs2; ec=ec2; w=w2; soff=NROWS; lr=row-NROWS; }
  float acc[8];
  #pragma unroll
  for (int j=0;j<8;j++) acc[j] = bias[g*8+j];
  const int s = rs[lr], e = rs[lr+1];
  int k = s;
  for (; k+4 <= e; k+=4){
    int c0=ec[k], c1=ec[k+1], c2=ec[k+2], c3=ec[k+3];
    float f0=w[k], f1=w[k+1], f2=w[k+2], f3=w[k+3];
    int4 v0 = *(const int4*)(sup + (long)(soff+c0)*C + g*8);
    int4 v1 = *(const int4*)(sup + (long)(soff+c1)*C + g*8);
    int4 v2 = *(const int4*)(sup + (long)(soff+c2)*C + g*8);
    int4 v3 = *(const int4*)(sup + (long)(soff+c3)*C + g*8);
    acc8(acc, v0, f0); acc8(acc, v1, f1); acc8(acc, v2, f2); acc8(acc, v3, f3);
  }
  for (; k < e; k++){
    int c0=ec[k]; float f0=w[k];
    int4 v0 = *(const int4*)(sup + (long)(soff+c0)*C + g*8);
    acc8(acc, v0, f0);
  }
  int4 ov;
  unsigned* ou = (unsigned*)&ov;
  #pragma unroll
  for (int i=0;i<4;i++){
    float a0 = acc[2*i], a1 = acc[2*i+1];
    if (RELU){ a0 = fmaxf(a0,0.f); a1 = fmaxf(a1,0.f); }
    unsigned p0 = (unsigned)(unsigned short)f2bf(a0);
    unsigned p1 = (unsigned)(unsigned short)f2bf(a1);
    ou[i] = p0 | (p1<<16);
  }
  *(int4*)(out + (long)row*C + g*8) = ov;
}

// ---- normalize rows of z (fp32 [16384,128]) -> bf16 z_n; also bdot[i] = z1n_i . z2n_i ----
__global__ __launch_bounds__(256) void norm_k(const float* __restrict__ z, short* __restrict__ znb,
                                              float* __restrict__ bdot){
  int wave = threadIdx.x>>6, lane = threadIdx.x&63;
  int i = blockIdx.x*4 + wave;   // 0..8191 (pair rows i and i+8192)
  const float* za = z + (long)i*128;
  const float* zb = z + (long)(i+NROWS)*128;
  float a0=za[lane], a1=za[lane+64], b0=zb[lane], b1=zb[lane+64];
  float sa = a0*a0 + a1*a1;
  float sb = b0*b0 + b1*b1;
  #pragma unroll
  for (int m=1;m<64;m<<=1){ sa += __shfl_xor(sa,m); sb += __shfl_xor(sb,m); }
  float ra = 1.f / fmaxf(sqrtf(sa), 1e-12f);
  float rb = 1.f / fmaxf(sqrtf(sb), 1e-12f);
  short* oa = znb + (long)i*128;
  short* ob = znb + (long)(i+NROWS)*128;
  oa[lane] = f2bf(a0*ra); oa[lane+64] = f2bf(a1*ra);
  ob[lane] = f2bf(b0*rb); ob[lane+64] = f2bf(b1*rb);
  float d = (a0*ra)*(b0*rb) + (a1*ra)*(b1*rb);
  #pragma unroll
  for (int m=1;m<64;m<<=1) d += __shfl_xor(d,m);
  if (lane==0) bdot[i] = d;
}

// ---- streamed exp-Gram: S = A @ B^T (128x128 tile per block, K=128, bf16 MFMA),
// rowsum += sum_j exp(2*S_ij); MODE 1: also colsum += sum_i (between matrix).
// MODE 2: symmetric (A==B): only upper-tri blocks; mirror col-sums into rowsum.
template<int MODE>
__global__ __launch_bounds__(256) void gram_k(const short* __restrict__ A, const short* __restrict__ B,
                                              float* __restrict__ rowsum, float* __restrict__ colsum){
  const int bx = blockIdx.x, by = blockIdx.y;
  if (MODE==2 && by < bx) return;
  __shared__ short As[128*136];   // +8 pad: 272B row stride, 16B aligned
  __shared__ short Bs[128*136];
  const int i0 = bx*128, j0 = by*128;
  const int tid = threadIdx.x;
  #pragma unroll
  for (int p=0;p<8;p++){
    int idx = p*256 + tid;
    int r = idx >> 4, cc = (idx & 15)*8;
    *(int4*)&As[r*136 + cc] = *(const int4*)(A + (long)(i0+r)*128 + cc);
    *(int4*)&Bs[r*136 + cc] = *(const int4*)(B + (long)(j0+r)*128 + cc);
  }
  __syncthreads();
  const int wave = tid>>6, lane = tid&63, quad = lane>>4, cl = lane&15;
  const int wm = (wave&1)*64, wn = (wave>>1)*64;
  f32x4 zero = {0.f,0.f,0.f,0.f};
  f32x4 acc[4][4];
  #pragma unroll
  for (int i=0;i<4;i++)
    #pragma unroll
    for (int j=0;j<4;j++) acc[i][j]=zero;
  #pragma unroll
  for (int kc=0;kc<4;kc++){
    const int ko = kc*32 + quad*8;
    bf16x8 a[4], b[4];
    #pragma unroll
    for (int mt=0;mt<4;mt++) a[mt] = *(const bf16x8*)&As[(wm+mt*16+cl)*136 + ko];
    #pragma unroll
    for (int nt=0;nt<4;nt++) b[nt] = *(const bf16x8*)&Bs[(wn+nt*16+cl)*136 + ko];
    #pragma unroll
    for (int mt=0;mt<4;mt++)
      #pragma unroll
      for (int nt=0;nt<4;nt++)
        acc[mt][nt] = mfma16(a[mt], b[nt], acc[mt][nt]);
  }
  const bool diag = (MODE==2) && (bx==by);
  float csum[4] = {0.f,0.f,0.f,0.f};
  #pragma unroll
  for (int mt=0;mt<4;mt++){
    float rs[4] = {0.f,0.f,0.f,0.f};
    #pragma unroll
    for (int nt=0;nt<4;nt++){
      f32x4 v = acc[mt][nt];
      #pragma unroll
      for (int r=0;r<4;r++){
        float e = __expf(2.f*v[r]);   // 1/TEMP = 2
        rs[r] += e;
        csum[nt] += e;
      }
    }
    #pragma unroll
    for (int r=0;r<4;r++){
      float s = rs[r];
      s += __shfl_xor(s,1); s += __shfl_xor(s,2); s += __shfl_xor(s,4); s += __shfl_xor(s,8);
      if (cl==0) atomicAdd(&rowsum[i0+wm+mt*16+quad*4+r], s);
    }
  }
  if (MODE==1 || (MODE==2 && !diag)){
    #pragma unroll
    for (int nt=0;nt<4;nt++){
      float s = csum[nt];
      s += __shfl_xor(s,16); s += __shfl_xor(s,32);
      if (quad==0){
        float* dst = (MODE==1) ? colsum : rowsum;  // symmetric: mirror into rowsum
        atomicAdd(&dst[j0+wn+nt*16+cl], s);
      }
    }
  }
}

// ---- final loss ----
__global__ void loss_k(const float* __restrict__ r1, const float* __restrict__ r2,
                       const float* __restrict__ brow, const float* __restrict__ bcol,
                       const float* __restrict__ bdot, float* __restrict__ out){
  __shared__ float red[256];
  const float E2 = 7.3890560989306495f;  // exp(2) = diag(refl)
  int t = threadIdx.x;
  float s = 0.f;
  for (int i=t;i<NROWS;i+=256){
    float lb = 2.f * bdot[i];            // log(between_ii), fp32 exact
    float d1 = r1[i] + brow[i] - E2;
    float d2 = r2[i] + bcol[i] - E2;
    s += 0.5f * ((logf(d1) - lb) + (logf(d2) - lb));
  }
  red[t]=s; __syncthreads();
  for (int st=128; st>0; st>>=1){ if (t<st) red[t]+=red[t+st]; __syncthreads(); }
  if (t==0) out[0] = red[0] / (float)NROWS;
}

extern "C" void kernel_launch(void* const* d_in, const int* in_sizes, int n_in,
                              void* d_out, int out_size, void* d_ws, size_t ws_size,
                              hipStream_t stream){
  const float* feat1 = (const float*)d_in[0];
  const float* feat2 = (const float*)d_in[1];
  const int*   ei1   = (const int*)d_in[2];
  const float* w1    = (const float*)d_in[3];
  const int*   ei2   = (const int*)d_in[4];
  const float* w2    = (const float*)d_in[5];
  const float* w_l1a = (const float*)d_in[6];
  const float* b_l1a = (const float*)d_in[7];
  const float* w_l1b = (const float*)d_in[8];
  const float* b_l1b = (const float*)d_in[9];
  const float* w_g1  = (const float*)d_in[10];
  const float* b_g1  = (const float*)d_in[11];
  const float* w_g2  = (const float*)d_in[12];
  const float* b_g2  = (const float*)d_in[13];
  const float* w_fc1 = (const float*)d_in[14];
  const float* b_fc1 = (const float*)d_in[15];
  const float* w_fc2 = (const float*)d_in[16];
  const float* b_fc2 = (const float*)d_in[17];

  char* base = (char*)d_ws;
  size_t off = 0;
  auto alloc = [&](size_t bytes)->void*{
    void* r = base + off;
    off = (off + bytes + 255) & ~(size_t)255;
    return r;
  };
  float* z    = (float*)alloc((size_t)MROWS*128*4);
  short* znb  = (short*)alloc((size_t)MROWS*128*2);
  short* a1   = (short*)alloc((size_t)MROWS*64*2);
  short* xb   = (short*)alloc((size_t)MROWS*32*2);
  short* s1   = (short*)alloc((size_t)MROWS*256*2);
  short* hb   = (short*)alloc((size_t)MROWS*256*2);
  short* s2   = (short*)alloc((size_t)MROWS*128*2);
  short* hh   = (short*)alloc((size_t)MROWS*128*2);
  short* t2   = (short*)alloc((size_t)MROWS*64*2);
  short* wl1a_t = (short*)alloc(512*64*2);
  short* wl1b_t = (short*)alloc(64*32*2);
  short* wg1_t  = (short*)alloc(32*256*2);
  short* wg2_t  = (short*)alloc(256*128*2);
  short* wfc1_t = (short*)alloc(128*64*2);
  short* wfc2_t = (short*)alloc(64*128*2);
  // contiguous zero region: deg1 deg2 r1s r2s brow bcol (one memset)
  int*   deg1 = (int*)alloc(NROWS*4);
  int*   deg2 = (int*)alloc(NROWS*4);
  float* r1s  = (float*)alloc(NROWS*4);
  float* r2s  = (float*)alloc(NROWS*4);
  float* brow = (float*)alloc(NROWS*4);
  float* bcol = (float*)alloc(NROWS*4);
  int* rs1  = (int*)alloc((NROWS+1)*4);
  int* cur1 = (int*)alloc(NROWS*4);
  int* rs2  = (int*)alloc((NROWS+1)*4);
  int* cur2 = (int*)alloc(NROWS*4);
  int*   ecol1 = (int*)alloc((size_t)NEDGE*4);
  float* ewt1  = (float*)alloc((size_t)NEDGE*4);
  int*   ecol2 = (int*)alloc((size_t)NEDGE*4);
  float* ewt2  = (float*)alloc((size_t)NEDGE*4);
  float* bdot  = (float*)alloc(NROWS*4);

  hipMemsetAsync(deg1, 0, (size_t)6*NROWS*4, stream);

  wt_k<<<(512*64+255)/256,256,0,stream>>>(w_l1a, wl1a_t, 512, 64);
  wt_k<<<(64*32+255)/256,256,0,stream>>>(w_l1b, wl1b_t, 64, 32);
  wt_k<<<(32*256+255)/256,256,0,stream>>>(w_g1, wg1_t, 32, 256);
  wt_k<<<(256*128+255)/256,256,0,stream>>>(w_g2, wg2_t, 256, 128);
  wt_k<<<(128*64+255)/256,256,0,stream>>>(w_fc1, wfc1_t, 128, 64);
  wt_k<<<(64*128+255)/256,256,0,stream>>>(w_fc2, wfc2_t, 64, 128);

  hist_k<<<NEDGE/256,256,0,stream>>>(ei1, deg1);
  hist_k<<<NEDGE/256,256,0,stream>>>(ei2, deg2);
  scan_k<<<1,256,0,stream>>>(deg1, rs1, cur1);
  scan_k<<<1,256,0,stream>>>(deg2, rs2, cur2);
  fill_k<<<NEDGE/256,256,0,stream>>>(ei1, w1, cur1, ecol1, ewt1);
  fill_k<<<NEDGE/256,256,0,stream>>>(ei2, w2, cur2, ecol2, ewt2);

  // encoder (both graphs batched: rows 0..8191 = view1, 8192..16383 = view2)
  gemm_k<64,512,1,true,true,false><<<MROWS/64,256,0,stream>>>(feat1, feat2, wl1a_t, b_l1a, a1);
  gemm_k<32,64,0,false,true,false><<<MROWS/64,256,0,stream>>>(a1, nullptr, wl1b_t, b_l1b, xb);
  gemm_k<256,32,0,false,false,false><<<MROWS/64,256,0,stream>>>(xb, nullptr, wg1_t, nullptr, s1);
  gather_k<256,true><<<MROWS/8,256,0,stream>>>(s1, rs1,ecol1,ewt1, rs2,ecol2,ewt2, b_g1, hb);
  gemm_k<128,256,0,false,false,false><<<MROWS/64,256,0,stream>>>(hb, nullptr, wg2_t, nullptr, s2);
  gather_k<128,false><<<MROWS/16,256,0,stream>>>(s2, rs1,ecol1,ewt1, rs2,ecol2,ewt2, b_g2, hh);
  // projection
  gemm_k<64,128,2,false,true,false><<<MROWS/64,256,0,stream>>>(hh, nullptr, wfc1_t, b_fc1, t2);
  gemm_k<128,64,0,false,true,true><<<MROWS/64,256,0,stream>>>(t2, nullptr, wfc2_t, b_fc2, z);

  norm_k<<<NROWS/4,256,0,stream>>>(z, znb, bdot);

  dim3 gg(64,64);
  const short* z1b = znb;
  const short* z2b = znb + (size_t)NROWS*128;
  gram_k<2><<<gg,256,0,stream>>>(z1b, z1b, r1s, nullptr);
  gram_k<2><<<gg,256,0,stream>>>(z2b, z2b, r2s, nullptr);
  gram_k<1><<<gg,256,0,stream>>>(z1b, z2b, brow, bcol);

  loss_k<<<1,256,0,stream>>>(r1s, r2s, brow, bcol, bdot, (float*)d_out);
}

// Round 3
// 374.497 us; speedup vs baseline: 1.6632x; 1.1238x over previous
//
#include <hip/hip_runtime.h>
#include <hip/hip_bf16.h>
#include <math.h>

// GRACE-style graph contrastive loss, MI355X (gfx950).
// R3: fused single symmetric exp-Gram over Z=[z1n;z2n] (fp8 e4m3 MFMA, XOR-swizzled
// LDS, 256x256 super-tiles, upper-tri + mirror), fp8 quantize in norm_k,
// fused setup kernels (wt/hist/scan/fill). R2 profile: 3x gram_k = 182us at
// MfmaUtil 10% / 19% occupancy / 2.1M LDS conflicts; structural floor ~20us.

#define NROWS 8192
#define MROWS 16384
#define NEDGE 262144

typedef __attribute__((ext_vector_type(8))) short bf16x8;
typedef __attribute__((ext_vector_type(4))) float f32x4;
typedef __attribute__((ext_vector_type(2))) float f32x2;

__device__ __forceinline__ float bf2f(short s){
  union { unsigned u; float f; } cv; cv.u = ((unsigned)(unsigned short)s) << 16; return cv.f;
}
__device__ __forceinline__ short f2bf(float f){
  union { float f; unsigned u; } cv; cv.f = f;
  unsigned u = cv.u;
  unsigned r = (u + 0x7fffu + ((u >> 16) & 1u)) >> 16;  // RNE; inputs finite
  return (short)r;
}
__device__ __forceinline__ f32x4 mfma16(bf16x8 a, bf16x8 b, f32x4 c){
  return __builtin_amdgcn_mfma_f32_16x16x32_bf16(a, b, c, 0, 0, 0);
}

// ---- fp8 e4m3fn pack (RNE) ----
__device__ unsigned char f2e4m3_sw(float f){
  float a = fabsf(f);
  unsigned s = (__float_as_uint(f)>>24)&0x80u;
  if (!(a>0.f)) return (unsigned char)s;
  if (a>448.f) a=448.f;
  int e; frexpf(a,&e);
  int eff=e-1;
  unsigned code;
  if (eff<-6){
    float q=rintf(a*512.f);
    code=(unsigned)q; if(code>7)code=7;
  } else {
    float q=rintf(a*exp2f((float)(3-eff)));
    unsigned mant=(unsigned)q;
    if(mant>=16){mant=8;eff++;}
    if(eff>8) return (unsigned char)(s|0x7e);
    code=((unsigned)(eff+7)<<3)|(mant-8);
  }
  return (unsigned char)(s|code);
}
__device__ __forceinline__ unsigned short pack2fp8(float a, float b){
#if __has_builtin(__builtin_amdgcn_cvt_pk_fp8_f32)
  int v = __builtin_amdgcn_cvt_pk_fp8_f32(a, b, 0, false);
  return (unsigned short)(v & 0xffff);
#else
  return (unsigned short)((unsigned)f2e4m3_sw(a) | ((unsigned)f2e4m3_sw(b)<<8));
#endif
}

// ---- fused weight transpose + bf16 cast for all 6 weights ----
struct WtArgs {
  const float* src[6];
  short* dst[6];
  int K[6], N[6];
  int off[7];
};
__global__ void wtall_k(WtArgs a){
  int i = blockIdx.x*256 + threadIdx.x;
  if (i >= a.off[6]) return;
  int s = 0;
  #pragma unroll
  for (int j=1;j<6;j++) if (i >= a.off[j]) s=j;
  int l = i - a.off[s];
  int K=a.K[s], N=a.N[s];
  int k=l/N, n=l-k*N;
  a.dst[s][(long)n*K+k] = f2bf(a.src[s][l]);
}

// ---- generic tall-skinny MFMA GEMM: Out[M,NN] = act(A[M,KK] @ Bt[NN,KK]^T + bias) ----
template<int NN, int KK, int ACT, bool AFP32, bool BIAS, bool OUTF32>
__global__ __launch_bounds__(256) void gemm_k(const void* __restrict__ A0, const void* __restrict__ A1,
                                              const short* __restrict__ Bt, const float* __restrict__ bias,
                                              void* __restrict__ Out){
  constexpr int WM = (NN >= 64) ? 64 : 16;
  constexpr int WN = (NN >= 64) ? (NN/4) : NN;
  constexpr int MT = WM/16, NT = WN/16;
  const int tid = threadIdx.x;
  const int wave = tid >> 6, lane = tid & 63, quad = lane >> 4, cl = lane & 15;
  const int m0 = blockIdx.x * 64;
  const int wmo = (NN >= 64) ? 0 : wave*16;
  const int wno = (NN >= 64) ? wave*WN : 0;

  f32x4 zero = {0.f,0.f,0.f,0.f};
  f32x4 acc[MT][NT];
  #pragma unroll
  for (int i=0;i<MT;i++)
    #pragma unroll
    for (int j=0;j<NT;j++) acc[i][j] = zero;

  #pragma unroll
  for (int kc = 0; kc < KK/32; kc++){
    const int ko = kc*32 + quad*8;
    bf16x8 a[MT], b[NT];
    #pragma unroll
    for (int mt=0; mt<MT; mt++){
      int row = m0 + wmo + mt*16 + cl;
      if constexpr (AFP32){
        const float* ar = (row < NROWS) ? ((const float*)A0 + (long)row*KK + ko)
                                        : ((const float*)A1 + (long)(row-NROWS)*KK + ko);
        float4 f0 = *(const float4*)ar;
        float4 f1 = *(const float4*)(ar+4);
        bf16x8 t;
        t[0]=f2bf(f0.x); t[1]=f2bf(f0.y); t[2]=f2bf(f0.z); t[3]=f2bf(f0.w);
        t[4]=f2bf(f1.x); t[5]=f2bf(f1.y); t[6]=f2bf(f1.z); t[7]=f2bf(f1.w);
        a[mt]=t;
      } else {
        a[mt] = *(const bf16x8*)((const short*)A0 + (long)row*KK + ko);
      }
    }
    #pragma unroll
    for (int nt=0; nt<NT; nt++)
      b[nt] = *(const bf16x8*)(Bt + (long)(wno + nt*16 + cl)*KK + ko);
    #pragma unroll
    for (int mt=0; mt<MT; mt++)
      #pragma unroll
      for (int nt=0; nt<NT; nt++)
        acc[mt][nt] = mfma16(a[mt], b[nt], acc[mt][nt]);
  }
  #pragma unroll
  for (int mt=0; mt<MT; mt++){
    #pragma unroll
    for (int nt=0; nt<NT; nt++){
      int col = wno + nt*16 + cl;
      float bv = 0.f;
      if constexpr (BIAS) bv = bias[col];
      #pragma unroll
      for (int r=0;r<4;r++){
        int row = m0 + wmo + mt*16 + quad*4 + r;
        float v = acc[mt][nt][r] + bv;
        if (ACT==1) v = fmaxf(v, 0.f);
        if (ACT==2) v = (v > 0.f) ? v : expm1f(v);
        if constexpr (OUTF32) ((float*)Out)[(long)row*NN + col] = v;
        else ((short*)Out)[(long)row*NN + col] = f2bf(v);
      }
    }
  }
}

// ---- CSR build (both graphs fused per kernel) ----
__global__ void hist2_k(const int* __restrict__ ei1, const int* __restrict__ ei2,
                        int* __restrict__ deg1, int* __restrict__ deg2){
  int b = blockIdx.x;
  const int* ei = (b < NEDGE/256) ? ei1 : ei2;
  int* deg = (b < NEDGE/256) ? deg1 : deg2;
  int e = (b % (NEDGE/256))*256 + threadIdx.x;
  atomicAdd(&deg[ei[e]], 1);
}
__global__ void scan2_k(const int* __restrict__ deg1, int* __restrict__ rs1, int* __restrict__ cur1,
                        const int* __restrict__ deg2, int* __restrict__ rs2, int* __restrict__ cur2){
  const int* deg = blockIdx.x ? deg2 : deg1;
  int* rowstart = blockIdx.x ? rs2 : rs1;
  int* cursor = blockIdx.x ? cur2 : cur1;
  __shared__ int csum[256];
  __shared__ int base[257];
  int t = threadIdx.x;
  int loc[32];
  int s = 0;
  for (int j=0;j<32;j++){ int d = deg[t*32+j]; loc[j] = s; s += d; }
  csum[t] = s;
  __syncthreads();
  if (t==0){ int a=0; for (int i=0;i<256;i++){ base[i]=a; a+=csum[i]; } base[256]=a; }
  __syncthreads();
  for (int j=0;j<32;j++){ int v = base[t] + loc[j]; rowstart[t*32+j]=v; cursor[t*32+j]=v; }
  if (t==0) rowstart[NROWS] = base[256];
}
__global__ void fill2_k(const int* __restrict__ ei1, const float* __restrict__ w1, int* __restrict__ cur1,
                        int* __restrict__ ecol1, float* __restrict__ ew1,
                        const int* __restrict__ ei2, const float* __restrict__ w2, int* __restrict__ cur2,
                        int* __restrict__ ecol2, float* __restrict__ ew2){
  int b = blockIdx.x;
  bool g2 = (b >= NEDGE/256);
  const int* ei = g2 ? ei2 : ei1;
  const float* w = g2 ? w2 : w1;
  int* cursor = g2 ? cur2 : cur1;
  int* ecol = g2 ? ecol2 : ecol1;
  float* ew = g2 ? ew2 : ew1;
  int e = (b % (NEDGE/256))*256 + threadIdx.x;
  int r = ei[e];
  int p = atomicAdd(&cursor[r], 1);
  ecol[p] = ei[NEDGE + e];
  ew[p] = w[e];
}

// ---- GCN aggregation (gather form), latency-optimized ----
__device__ __forceinline__ void acc8(float* acc, int4 v, float f){
  const unsigned* u = (const unsigned*)&v;
  #pragma unroll
  for (int i=0;i<4;i++){
    union{unsigned x; float y;} lo, hi;
    lo.x = u[i] << 16;
    hi.x = u[i] & 0xffff0000u;
    acc[2*i]   = fmaf(f, lo.y, acc[2*i]);
    acc[2*i+1] = fmaf(f, hi.y, acc[2*i+1]);
  }
}

template<int C, bool RELU>
__global__ __launch_bounds__(256) void gather_k(const short* __restrict__ sup,
    const int* __restrict__ rs1, const int* __restrict__ ec1, const float* __restrict__ w1,
    const int* __restrict__ rs2, const int* __restrict__ ec2, const float* __restrict__ w2,
    const float* __restrict__ bias, short* __restrict__ out){
  constexpr int G = C/8;
  constexpr int RPB = 256/G;
  const int g = threadIdx.x % G;
  const int sub = threadIdx.x / G;
  const int row = blockIdx.x*RPB + sub;
  const int* rs; const int* ec; const float* w; int soff, lr;
  if (row < NROWS){ rs=rs1; ec=ec1; w=w1; soff=0; lr=row; }
  else            { rs=rs2; ec=ec2; w=w2; soff=NROWS; lr=row-NROWS; }
  float acc[8];
  #pragma unroll
  for (int j=0;j<8;j++) acc[j] = bias[g*8+j];
  const int s = rs[lr], e = rs[lr+1];
  int k = s;
  for (; k+4 <= e; k+=4){
    int c0=ec[k], c1=ec[k+1], c2=ec[k+2], c3=ec[k+3];
    float f0=w[k], f1=w[k+1], f2=w[k+2], f3=w[k+3];
    int4 v0 = *(const int4*)(sup + (long)(soff+c0)*C + g*8);
    int4 v1 = *(const int4*)(sup + (long)(soff+c1)*C + g*8);
    int4 v2 = *(const int4*)(sup + (long)(soff+c2)*C + g*8);
    int4 v3 = *(const int4*)(sup + (long)(soff+c3)*C + g*8);
    acc8(acc, v0, f0); acc8(acc, v1, f1); acc8(acc, v2, f2); acc8(acc, v3, f3);
  }
  for (; k < e; k++){
    int c0=ec[k]; float f0=w[k];
    int4 v0 = *(const int4*)(sup + (long)(soff+c0)*C + g*8);
    acc8(acc, v0, f0);
  }
  int4 ov;
  unsigned* ou = (unsigned*)&ov;
  #pragma unroll
  for (int i=0;i<4;i++){
    float a0 = acc[2*i], a1 = acc[2*i+1];
    if (RELU){ a0 = fmaxf(a0,0.f); a1 = fmaxf(a1,0.f); }
    unsigned p0 = (unsigned)(unsigned short)f2bf(a0);
    unsigned p1 = (unsigned)(unsigned short)f2bf(a1);
    ou[i] = p0 | (p1<<16);
  }
  *(int4*)(out + (long)row*C + g*8) = ov;
}

// ---- normalize rows of z (fp32 [16384,128]) -> fp8 zq; bdot[i] = z1n_i . z2n_i (fp32) ----
__global__ __launch_bounds__(256) void norm_k(const float* __restrict__ z, unsigned short* __restrict__ zq,
                                              float* __restrict__ bdot){
  int wave = threadIdx.x>>6, lane = threadIdx.x&63;
  int i = blockIdx.x*4 + wave;   // row pair (i, i+8192)
  float2 a2 = *(const float2*)(z + (long)i*128 + lane*2);
  float2 b2 = *(const float2*)(z + (long)(i+NROWS)*128 + lane*2);
  float sa = a2.x*a2.x + a2.y*a2.y;
  float sb = b2.x*b2.x + b2.y*b2.y;
  #pragma unroll
  for (int m=1;m<64;m<<=1){ sa += __shfl_xor(sa,m); sb += __shfl_xor(sb,m); }
  float ra = 1.f / fmaxf(sqrtf(sa), 1e-12f);
  float rb = 1.f / fmaxf(sqrtf(sb), 1e-12f);
  zq[(long)i*64 + lane]         = pack2fp8(a2.x*ra, a2.y*ra);
  zq[(long)(i+NROWS)*64 + lane] = pack2fp8(b2.x*rb, b2.y*rb);
  float d = (a2.x*ra)*(b2.x*rb) + (a2.y*ra)*(b2.y*rb);
  #pragma unroll
  for (int m=1;m<64;m<<=1) d += __shfl_xor(d,m);
  if (lane==0) bdot[i] = d;
}

// ---- fused symmetric exp-Gram row sums over Z[16384,128] fp8 ----
// S[r] += sum_c exp(2 * Z_r . Z_c) over all 16384 cols; upper-tri 64x64 super-grid of
// 256x256 blocks, mirror col-sums for off-diagonal. XOR-16B-chunk LDS swizzle.
__global__ __launch_bounds__(1024,4) void gram2_k(const unsigned char* __restrict__ Zq,
                                                  float* __restrict__ S){
  __shared__ __align__(16) unsigned char Zi[256*128];
  __shared__ __align__(16) unsigned char Zj[256*128];
  const int t = blockIdx.x;
  // decode (bi,bj), bi<=bj, T=64: band bi starts at bi*64 - bi*(bi-1)/2
  int bi = (int)((129.0f - sqrtf(129.0f*129.0f - 8.0f*(float)t)) * 0.5f);
  while ((bi+1)*64 - ((bi+1)*bi)/2 <= t) bi++;
  while (bi*64 - (bi*(bi-1))/2 > t) bi--;
  const int bj = bi + (t - (bi*64 - (bi*(bi-1))/2));
  const long I0 = (long)bi*256, J0 = (long)bj*256;
  const int tid = threadIdx.x;
  const bool diag = (bi==bj);
  {
    int r0 = tid>>3, c0 = tid&7;
    int r1 = (tid+1024)>>3, c1 = tid&7;
    *(int4*)&Zi[r0*128 + ((c0 ^ (r0&7))*16)] = *(const int4*)(Zq + (I0+r0)*128 + c0*16);
    *(int4*)&Zi[r1*128 + ((c1 ^ (r1&7))*16)] = *(const int4*)(Zq + (I0+r1)*128 + c1*16);
    if (!diag){
      *(int4*)&Zj[r0*128 + ((c0 ^ (r0&7))*16)] = *(const int4*)(Zq + (J0+r0)*128 + c0*16);
      *(int4*)&Zj[r1*128 + ((c1 ^ (r1&7))*16)] = *(const int4*)(Zq + (J0+r1)*128 + c1*16);
    }
  }
  __syncthreads();
  const unsigned char* Bs = diag ? Zi : Zj;
  const int wave = tid>>6, lane = tid&63, quad = lane>>4, cl = lane&15;
  const int wr = (wave>>2)*64, wc = (wave&3)*64;
  const int half8 = (quad&1)*8;
  const int chq = quad>>1;
  f32x4 zero = {0.f,0.f,0.f,0.f};
  f32x4 acc[4][4];
  #pragma unroll
  for (int i=0;i<4;i++)
    #pragma unroll
    for (int j=0;j<4;j++) acc[i][j]=zero;
  #pragma unroll
  for (int kc=0;kc<4;kc++){
    const int ch = 2*kc + chq;
    long long a[4], b[4];
    #pragma unroll
    for (int mt=0;mt<4;mt++){
      int R = wr + mt*16 + cl;
      a[mt] = *(const long long*)&Zi[R*128 + ((ch ^ (R&7))*16) + half8];
    }
    #pragma unroll
    for (int nt=0;nt<4;nt++){
      int Cc = wc + nt*16 + cl;
      b[nt] = *(const long long*)&Bs[Cc*128 + ((ch ^ (Cc&7))*16) + half8];
    }
    #pragma unroll
    for (int mt=0;mt<4;mt++)
      #pragma unroll
      for (int nt=0;nt<4;nt++)
        acc[mt][nt] = __builtin_amdgcn_mfma_f32_16x16x32_fp8_fp8(a[mt], b[nt], acc[mt][nt], 0, 0, 0);
  }
  const float KE = 2.8853900817779268f;  // (1/TEMP)*log2(e) = 2*log2(e)
  f32x2 z2 = {0.f,0.f};
  f32x2 rs01[4] = {z2,z2,z2,z2}, rs23[4] = {z2,z2,z2,z2};
  f32x2 cs[4] = {z2,z2,z2,z2};
  #pragma unroll
  for (int mt=0;mt<4;mt++){
    #pragma unroll
    for (int nt=0;nt<4;nt++){
      f32x4 v = acc[mt][nt];
      float e0 = exp2f(v[0]*KE), e1 = exp2f(v[1]*KE);
      float e2 = exp2f(v[2]*KE), e3 = exp2f(v[3]*KE);
      f32x2 p01 = {e0,e1}, p23 = {e2,e3};
      rs01[mt] += p01; rs23[mt] += p23;
      cs[nt] += p01; cs[nt] += p23;
    }
  }
  // row-side: reduce over cl (16 cols) within quad
  #pragma unroll
  for (int mt=0;mt<4;mt++){
    union{f32x2 v; double d;} u0, u1;
    u0.v = rs01[mt]; u1.v = rs23[mt];
    #pragma unroll
    for (int m=1;m<16;m<<=1){
      union{double d; f32x2 v;} o0, o1;
      o0.d = __shfl_xor(u0.d, m); o1.d = __shfl_xor(u1.d, m);
      u0.v += o0.v; u1.v += o1.v;
    }
    if (cl==0){
      int R = (int)I0 + wr + mt*16 + quad*4;
      atomicAdd(&S[R+0], u0.v.x); atomicAdd(&S[R+1], u0.v.y);
      atomicAdd(&S[R+2], u1.v.x); atomicAdd(&S[R+3], u1.v.y);
    }
  }
  // col-side (mirror) for off-diagonal blocks: reduce over quads (16 rows each)
  if (!diag){
    #pragma unroll
    for (int nt=0;nt<4;nt++){
      float s = cs[nt].x + cs[nt].y;
      s += __shfl_xor(s,16); s += __shfl_xor(s,32);
      if (quad==0) atomicAdd(&S[(int)J0 + wc + nt*16 + cl], s);
    }
  }
}

// ---- final loss: mean_i 0.5*[(log(S[i]-E2) - 2 bdot) + (log(S[8192+i]-E2) - 2 bdot)] ----
__global__ void loss_k(const float* __restrict__ S, const float* __restrict__ bdot,
                       float* __restrict__ out){
  __shared__ float red[256];
  const float E2 = 7.3890560989306495f;  // exp(2) = diag(refl)
  int t = threadIdx.x;
  float s = 0.f;
  for (int i=t;i<NROWS;i+=256){
    float lb = 2.f * bdot[i];
    float d1 = S[i] - E2;
    float d2 = S[NROWS+i] - E2;
    s += 0.5f * ((logf(d1) - lb) + (logf(d2) - lb));
  }
  red[t]=s; __syncthreads();
  for (int st=128; st>0; st>>=1){ if (t<st) red[t]+=red[t+st]; __syncthreads(); }
  if (t==0) out[0] = red[0] / (float)NROWS;
}

extern "C" void kernel_launch(void* const* d_in, const int* in_sizes, int n_in,
                              void* d_out, int out_size, void* d_ws, size_t ws_size,
                              hipStream_t stream){
  const float* feat1 = (const float*)d_in[0];
  const float* feat2 = (const float*)d_in[1];
  const int*   ei1   = (const int*)d_in[2];
  const float* w1    = (const float*)d_in[3];
  const int*   ei2   = (const int*)d_in[4];
  const float* w2    = (const float*)d_in[5];
  const float* w_l1a = (const float*)d_in[6];
  const float* b_l1a = (const float*)d_in[7];
  const float* w_l1b = (const float*)d_in[8];
  const float* b_l1b = (const float*)d_in[9];
  const float* w_g1  = (const float*)d_in[10];
  const float* b_g1  = (const float*)d_in[11];
  const float* w_g2  = (const float*)d_in[12];
  const float* b_g2  = (const float*)d_in[13];
  const float* w_fc1 = (const float*)d_in[14];
  const float* b_fc1 = (const float*)d_in[15];
  const float* w_fc2 = (const float*)d_in[16];
  const float* b_fc2 = (const float*)d_in[17];

  char* base = (char*)d_ws;
  size_t off = 0;
  auto alloc = [&](size_t bytes)->void*{
    void* r = base + off;
    off = (off + bytes + 255) & ~(size_t)255;
    return r;
  };
  float* z    = (float*)alloc((size_t)MROWS*128*4);
  unsigned short* zq = (unsigned short*)alloc((size_t)MROWS*128);   // fp8 [16384,128]
  short* a1   = (short*)alloc((size_t)MROWS*64*2);
  short* xb   = (short*)alloc((size_t)MROWS*32*2);
  short* s1   = (short*)alloc((size_t)MROWS*256*2);
  short* hb   = (short*)alloc((size_t)MROWS*256*2);
  short* s2   = (short*)alloc((size_t)MROWS*128*2);
  short* hh   = (short*)alloc((size_t)MROWS*128*2);
  short* t2   = (short*)alloc((size_t)MROWS*64*2);
  short* wl1a_t = (short*)alloc(512*64*2);
  short* wl1b_t = (short*)alloc(64*32*2);
  short* wg1_t  = (short*)alloc(32*256*2);
  short* wg2_t  = (short*)alloc(256*128*2);
  short* wfc1_t = (short*)alloc(128*64*2);
  short* wfc2_t = (short*)alloc(64*128*2);
  // contiguous zero region: deg1 deg2 S (one memset)
  int*   deg1 = (int*)alloc(NROWS*4);
  int*   deg2 = (int*)alloc(NROWS*4);
  float* S    = (float*)alloc((size_t)MROWS*4);
  int* rs1  = (int*)alloc((NROWS+1)*4);
  int* cur1 = (int*)alloc(NROWS*4);
  int* rs2  = (int*)alloc((NROWS+1)*4);
  int* cur2 = (int*)alloc(NROWS*4);
  int*   ecol1 = (int*)alloc((size_t)NEDGE*4);
  float* ewt1  = (float*)alloc((size_t)NEDGE*4);
  int*   ecol2 = (int*)alloc((size_t)NEDGE*4);
  float* ewt2  = (float*)alloc((size_t)NEDGE*4);
  float* bdot  = (float*)alloc(NROWS*4);

  hipMemsetAsync(deg1, 0, (size_t)(2*NROWS + MROWS)*4, stream);

  WtArgs wa;
  wa.src[0]=w_l1a; wa.dst[0]=wl1a_t; wa.K[0]=512; wa.N[0]=64;
  wa.src[1]=w_l1b; wa.dst[1]=wl1b_t; wa.K[1]=64;  wa.N[1]=32;
  wa.src[2]=w_g1;  wa.dst[2]=wg1_t;  wa.K[2]=32;  wa.N[2]=256;
  wa.src[3]=w_g2;  wa.dst[3]=wg2_t;  wa.K[3]=256; wa.N[3]=128;
  wa.src[4]=w_fc1; wa.dst[4]=wfc1_t; wa.K[4]=128; wa.N[4]=64;
  wa.src[5]=w_fc2; wa.dst[5]=wfc2_t; wa.K[5]=64;  wa.N[5]=128;
  wa.off[0]=0;
  for (int i=0;i<6;i++) wa.off[i+1] = wa.off[i] + wa.K[i]*wa.N[i];
  wtall_k<<<(wa.off[6]+255)/256,256,0,stream>>>(wa);

  hist2_k<<<2*(NEDGE/256),256,0,stream>>>(ei1, ei2, deg1, deg2);
  scan2_k<<<2,256,0,stream>>>(deg1, rs1, cur1, deg2, rs2, cur2);
  fill2_k<<<2*(NEDGE/256),256,0,stream>>>(ei1, w1, cur1, ecol1, ewt1,
                                          ei2, w2, cur2, ecol2, ewt2);

  // encoder (both graphs batched: rows 0..8191 = view1, 8192..16383 = view2)
  gemm_k<64,512,1,true,true,false><<<MROWS/64,256,0,stream>>>(feat1, feat2, wl1a_t, b_l1a, a1);
  gemm_k<32,64,0,false,true,false><<<MROWS/64,256,0,stream>>>(a1, nullptr, wl1b_t, b_l1b, xb);
  gemm_k<256,32,0,false,false,false><<<MROWS/64,256,0,stream>>>(xb, nullptr, wg1_t, nullptr, s1);
  gather_k<256,true><<<MROWS/8,256,0,stream>>>(s1, rs1,ecol1,ewt1, rs2,ecol2,ewt2, b_g1, hb);
  gemm_k<128,256,0,false,false,false><<<MROWS/64,256,0,stream>>>(hb, nullptr, wg2_t, nullptr, s2);
  gather_k<128,false><<<MROWS/16,256,0,stream>>>(s2, rs1,ecol1,ewt1, rs2,ecol2,ewt2, b_g2, hh);
  // projection
  gemm_k<64,128,2,false,true,false><<<MROWS/64,256,0,stream>>>(hh, nullptr, wfc1_t, b_fc1, t2);
  gemm_k<128,64,0,false,true,true><<<MROWS/64,256,0,stream>>>(t2, nullptr, wfc2_t, b_fc2, z);

  norm_k<<<NROWS/4,256,0,stream>>>(z, zq, bdot);

  gram2_k<<<2080,1024,0,stream>>>((const unsigned char*)zq, S);

  loss_k<<<1,256,0,stream>>>(S, bdot, (float*)d_out);
}

// Round 4
// 341.023 us; speedup vs baseline: 1.8264x; 1.0982x over previous
//
#include <hip/hip_runtime.h>
#include <hip/hip_bf16.h>
#include <math.h>

// GRACE-style graph contrastive loss, MI355X (gfx950).
// R4: gram2_k atomic-free — per-block partial slices P[64][64][256] + reduceS_k.
// R3 post-mortem: gram2 was epilogue-VALU-bound + L2-thrashed by global atomics
// (WRITE_SIZE 41MB for a 64KB output); LDS "conflicts" were b64 width-cycles, benign.

#define NROWS 8192
#define MROWS 16384
#define NEDGE 262144

typedef __attribute__((ext_vector_type(8))) short bf16x8;
typedef __attribute__((ext_vector_type(4))) float f32x4;
typedef __attribute__((ext_vector_type(2))) float f32x2;

__device__ __forceinline__ float bf2f(short s){
  union { unsigned u; float f; } cv; cv.u = ((unsigned)(unsigned short)s) << 16; return cv.f;
}
__device__ __forceinline__ short f2bf(float f){
  union { float f; unsigned u; } cv; cv.f = f;
  unsigned u = cv.u;
  unsigned r = (u + 0x7fffu + ((u >> 16) & 1u)) >> 16;  // RNE; inputs finite
  return (short)r;
}
__device__ __forceinline__ f32x4 mfma16(bf16x8 a, bf16x8 b, f32x4 c){
  return __builtin_amdgcn_mfma_f32_16x16x32_bf16(a, b, c, 0, 0, 0);
}

// ---- fp8 e4m3fn pack (RNE) ----
__device__ unsigned char f2e4m3_sw(float f){
  float a = fabsf(f);
  unsigned s = (__float_as_uint(f)>>24)&0x80u;
  if (!(a>0.f)) return (unsigned char)s;
  if (a>448.f) a=448.f;
  int e; frexpf(a,&e);
  int eff=e-1;
  unsigned code;
  if (eff<-6){
    float q=rintf(a*512.f);
    code=(unsigned)q; if(code>7)code=7;
  } else {
    float q=rintf(a*exp2f((float)(3-eff)));
    unsigned mant=(unsigned)q;
    if(mant>=16){mant=8;eff++;}
    if(eff>8) return (unsigned char)(s|0x7e);
    code=((unsigned)(eff+7)<<3)|(mant-8);
  }
  return (unsigned char)(s|code);
}
__device__ __forceinline__ unsigned short pack2fp8(float a, float b){
#if __has_builtin(__builtin_amdgcn_cvt_pk_fp8_f32)
  int v = __builtin_amdgcn_cvt_pk_fp8_f32(a, b, 0, false);
  return (unsigned short)(v & 0xffff);
#else
  return (unsigned short)((unsigned)f2e4m3_sw(a) | ((unsigned)f2e4m3_sw(b)<<8));
#endif
}

// ---- fused weight transpose + bf16 cast for all 6 weights ----
struct WtArgs {
  const float* src[6];
  short* dst[6];
  int K[6], N[6];
  int off[7];
};
__global__ void wtall_k(WtArgs a){
  int i = blockIdx.x*256 + threadIdx.x;
  if (i >= a.off[6]) return;
  int s = 0;
  #pragma unroll
  for (int j=1;j<6;j++) if (i >= a.off[j]) s=j;
  int l = i - a.off[s];
  int K=a.K[s], N=a.N[s];
  int k=l/N, n=l-k*N;
  a.dst[s][(long)n*K+k] = f2bf(a.src[s][l]);
}

// ---- generic tall-skinny MFMA GEMM: Out[M,NN] = act(A[M,KK] @ Bt[NN,KK]^T + bias) ----
template<int NN, int KK, int ACT, bool AFP32, bool BIAS, bool OUTF32>
__global__ __launch_bounds__(256) void gemm_k(const void* __restrict__ A0, const void* __restrict__ A1,
                                              const short* __restrict__ Bt, const float* __restrict__ bias,
                                              void* __restrict__ Out){
  constexpr int WM = (NN >= 64) ? 64 : 16;
  constexpr int WN = (NN >= 64) ? (NN/4) : NN;
  constexpr int MT = WM/16, NT = WN/16;
  const int tid = threadIdx.x;
  const int wave = tid >> 6, lane = tid & 63, quad = lane >> 4, cl = lane & 15;
  const int m0 = blockIdx.x * 64;
  const int wmo = (NN >= 64) ? 0 : wave*16;
  const int wno = (NN >= 64) ? wave*WN : 0;

  f32x4 zero = {0.f,0.f,0.f,0.f};
  f32x4 acc[MT][NT];
  #pragma unroll
  for (int i=0;i<MT;i++)
    #pragma unroll
    for (int j=0;j<NT;j++) acc[i][j] = zero;

  #pragma unroll
  for (int kc = 0; kc < KK/32; kc++){
    const int ko = kc*32 + quad*8;
    bf16x8 a[MT], b[NT];
    #pragma unroll
    for (int mt=0; mt<MT; mt++){
      int row = m0 + wmo + mt*16 + cl;
      if constexpr (AFP32){
        const float* ar = (row < NROWS) ? ((const float*)A0 + (long)row*KK + ko)
                                        : ((const float*)A1 + (long)(row-NROWS)*KK + ko);
        float4 f0 = *(const float4*)ar;
        float4 f1 = *(const float4*)(ar+4);
        bf16x8 t;
        t[0]=f2bf(f0.x); t[1]=f2bf(f0.y); t[2]=f2bf(f0.z); t[3]=f2bf(f0.w);
        t[4]=f2bf(f1.x); t[5]=f2bf(f1.y); t[6]=f2bf(f1.z); t[7]=f2bf(f1.w);
        a[mt]=t;
      } else {
        a[mt] = *(const bf16x8*)((const short*)A0 + (long)row*KK + ko);
      }
    }
    #pragma unroll
    for (int nt=0; nt<NT; nt++)
      b[nt] = *(const bf16x8*)(Bt + (long)(wno + nt*16 + cl)*KK + ko);
    #pragma unroll
    for (int mt=0; mt<MT; mt++)
      #pragma unroll
      for (int nt=0; nt<NT; nt++)
        acc[mt][nt] = mfma16(a[mt], b[nt], acc[mt][nt]);
  }
  #pragma unroll
  for (int mt=0; mt<MT; mt++){
    #pragma unroll
    for (int nt=0; nt<NT; nt++){
      int col = wno + nt*16 + cl;
      float bv = 0.f;
      if constexpr (BIAS) bv = bias[col];
      #pragma unroll
      for (int r=0;r<4;r++){
        int row = m0 + wmo + mt*16 + quad*4 + r;
        float v = acc[mt][nt][r] + bv;
        if (ACT==1) v = fmaxf(v, 0.f);
        if (ACT==2) v = (v > 0.f) ? v : expm1f(v);
        if constexpr (OUTF32) ((float*)Out)[(long)row*NN + col] = v;
        else ((short*)Out)[(long)row*NN + col] = f2bf(v);
      }
    }
  }
}

// ---- CSR build (both graphs fused per kernel) ----
__global__ void hist2_k(const int* __restrict__ ei1, const int* __restrict__ ei2,
                        int* __restrict__ deg1, int* __restrict__ deg2){
  int b = blockIdx.x;
  const int* ei = (b < NEDGE/256) ? ei1 : ei2;
  int* deg = (b < NEDGE/256) ? deg1 : deg2;
  int e = (b % (NEDGE/256))*256 + threadIdx.x;
  atomicAdd(&deg[ei[e]], 1);
}
__global__ void scan2_k(const int* __restrict__ deg1, int* __restrict__ rs1, int* __restrict__ cur1,
                        const int* __restrict__ deg2, int* __restrict__ rs2, int* __restrict__ cur2){
  const int* deg = blockIdx.x ? deg2 : deg1;
  int* rowstart = blockIdx.x ? rs2 : rs1;
  int* cursor = blockIdx.x ? cur2 : cur1;
  __shared__ int csum[256];
  __shared__ int base[257];
  int t = threadIdx.x;
  int loc[32];
  int s = 0;
  for (int j=0;j<32;j++){ int d = deg[t*32+j]; loc[j] = s; s += d; }
  csum[t] = s;
  __syncthreads();
  if (t==0){ int a=0; for (int i=0;i<256;i++){ base[i]=a; a+=csum[i]; } base[256]=a; }
  __syncthreads();
  for (int j=0;j<32;j++){ int v = base[t] + loc[j]; rowstart[t*32+j]=v; cursor[t*32+j]=v; }
  if (t==0) rowstart[NROWS] = base[256];
}
__global__ void fill2_k(const int* __restrict__ ei1, const float* __restrict__ w1, int* __restrict__ cur1,
                        int* __restrict__ ecol1, float* __restrict__ ew1,
                        const int* __restrict__ ei2, const float* __restrict__ w2, int* __restrict__ cur2,
                        int* __restrict__ ecol2, float* __restrict__ ew2){
  int b = blockIdx.x;
  bool g2 = (b >= NEDGE/256);
  const int* ei = g2 ? ei2 : ei1;
  const float* w = g2 ? w2 : w1;
  int* cursor = g2 ? cur2 : cur1;
  int* ecol = g2 ? ecol2 : ecol1;
  float* ew = g2 ? ew2 : ew1;
  int e = (b % (NEDGE/256))*256 + threadIdx.x;
  int r = ei[e];
  int p = atomicAdd(&cursor[r], 1);
  ecol[p] = ei[NEDGE + e];
  ew[p] = w[e];
}

// ---- GCN aggregation (gather form), latency-optimized ----
__device__ __forceinline__ void acc8(float* acc, int4 v, float f){
  const unsigned* u = (const unsigned*)&v;
  #pragma unroll
  for (int i=0;i<4;i++){
    union{unsigned x; float y;} lo, hi;
    lo.x = u[i] << 16;
    hi.x = u[i] & 0xffff0000u;
    acc[2*i]   = fmaf(f, lo.y, acc[2*i]);
    acc[2*i+1] = fmaf(f, hi.y, acc[2*i+1]);
  }
}

template<int C, bool RELU>
__global__ __launch_bounds__(256) void gather_k(const short* __restrict__ sup,
    const int* __restrict__ rs1, const int* __restrict__ ec1, const float* __restrict__ w1,
    const int* __restrict__ rs2, const int* __restrict__ ec2, const float* __restrict__ w2,
    const float* __restrict__ bias, short* __restrict__ out){
  constexpr int G = C/8;
  constexpr int RPB = 256/G;
  const int g = threadIdx.x % G;
  const int sub = threadIdx.x / G;
  const int row = blockIdx.x*RPB + sub;
  const int* rs; const int* ec; const float* w; int soff, lr;
  if (row < NROWS){ rs=rs1; ec=ec1; w=w1; soff=0; lr=row; }
  else            { rs=rs2; ec=ec2; w=w2; soff=NROWS; lr=row-NROWS; }
  float acc[8];
  #pragma unroll
  for (int j=0;j<8;j++) acc[j] = bias[g*8+j];
  const int s = rs[lr], e = rs[lr+1];
  int k = s;
  for (; k+4 <= e; k+=4){
    int c0=ec[k], c1=ec[k+1], c2=ec[k+2], c3=ec[k+3];
    float f0=w[k], f1=w[k+1], f2=w[k+2], f3=w[k+3];
    int4 v0 = *(const int4*)(sup + (long)(soff+c0)*C + g*8);
    int4 v1 = *(const int4*)(sup + (long)(soff+c1)*C + g*8);
    int4 v2 = *(const int4*)(sup + (long)(soff+c2)*C + g*8);
    int4 v3 = *(const int4*)(sup + (long)(soff+c3)*C + g*8);
    acc8(acc, v0, f0); acc8(acc, v1, f1); acc8(acc, v2, f2); acc8(acc, v3, f3);
  }
  for (; k < e; k++){
    int c0=ec[k]; float f0=w[k];
    int4 v0 = *(const int4*)(sup + (long)(soff+c0)*C + g*8);
    acc8(acc, v0, f0);
  }
  int4 ov;
  unsigned* ou = (unsigned*)&ov;
  #pragma unroll
  for (int i=0;i<4;i++){
    float a0 = acc[2*i], a1 = acc[2*i+1];
    if (RELU){ a0 = fmaxf(a0,0.f); a1 = fmaxf(a1,0.f); }
    unsigned p0 = (unsigned)(unsigned short)f2bf(a0);
    unsigned p1 = (unsigned)(unsigned short)f2bf(a1);
    ou[i] = p0 | (p1<<16);
  }
  *(int4*)(out + (long)row*C + g*8) = ov;
}

// ---- normalize rows of z (fp32 [16384,128]) -> fp8 zq; bdot[i] = z1n_i . z2n_i (fp32) ----
__global__ __launch_bounds__(256) void norm_k(const float* __restrict__ z, unsigned short* __restrict__ zq,
                                              float* __restrict__ bdot){
  int wave = threadIdx.x>>6, lane = threadIdx.x&63;
  int i = blockIdx.x*4 + wave;   // row pair (i, i+8192)
  float2 a2 = *(const float2*)(z + (long)i*128 + lane*2);
  float2 b2 = *(const float2*)(z + (long)(i+NROWS)*128 + lane*2);
  float sa = a2.x*a2.x + a2.y*a2.y;
  float sb = b2.x*b2.x + b2.y*b2.y;
  #pragma unroll
  for (int m=1;m<64;m<<=1){ sa += __shfl_xor(sa,m); sb += __shfl_xor(sb,m); }
  float ra = 1.f / fmaxf(sqrtf(sa), 1e-12f);
  float rb = 1.f / fmaxf(sqrtf(sb), 1e-12f);
  zq[(long)i*64 + lane]         = pack2fp8(a2.x*ra, a2.y*ra);
  zq[(long)(i+NROWS)*64 + lane] = pack2fp8(b2.x*rb, b2.y*rb);
  float d = (a2.x*ra)*(b2.x*rb) + (a2.y*ra)*(b2.y*rb);
  #pragma unroll
  for (int m=1;m<64;m<<=1) d += __shfl_xor(d,m);
  if (lane==0) bdot[i] = d;
}

// ---- fused symmetric exp-Gram partial sums over Z[16384,128] fp8 ----
// Upper-tri 64x64 super-grid of 256x256 blocks. Block (bi,bj) writes:
//   P[bi][bj][0..255] = per-row partial sums of exp(2*S) over its 256 cols
//   P[bj][bi][0..255] = per-col partials (mirror), off-diag only.
// No atomics anywhere. XOR-16B-chunk LDS swizzle for fragments.
__global__ __launch_bounds__(1024) void gram2_k(const unsigned char* __restrict__ Zq,
                                                float* __restrict__ P){
  __shared__ __align__(16) unsigned char Zi[256*128];
  __shared__ __align__(16) unsigned char Zj[256*128];
  __shared__ float Srow4[4][256];
  __shared__ float Scol4[4][256];
  const int t = blockIdx.x;
  // decode (bi,bj), bi<=bj, T=64: band bi starts at bi*64 - bi*(bi-1)/2
  int bi = (int)((129.0f - sqrtf(129.0f*129.0f - 8.0f*(float)t)) * 0.5f);
  while ((bi+1)*64 - ((bi+1)*bi)/2 <= t) bi++;
  while (bi*64 - (bi*(bi-1))/2 > t) bi--;
  const int bj = bi + (t - (bi*64 - (bi*(bi-1))/2));
  const long I0 = (long)bi*256, J0 = (long)bj*256;
  const int tid = threadIdx.x;
  const bool diag = (bi==bj);
  {
    int r0 = tid>>3, c0 = tid&7;
    int r1 = (tid+1024)>>3, c1 = tid&7;
    *(int4*)&Zi[r0*128 + ((c0 ^ (r0&7))*16)] = *(const int4*)(Zq + (I0+r0)*128 + c0*16);
    *(int4*)&Zi[r1*128 + ((c1 ^ (r1&7))*16)] = *(const int4*)(Zq + (I0+r1)*128 + c1*16);
    if (!diag){
      *(int4*)&Zj[r0*128 + ((c0 ^ (r0&7))*16)] = *(const int4*)(Zq + (J0+r0)*128 + c0*16);
      *(int4*)&Zj[r1*128 + ((c1 ^ (r1&7))*16)] = *(const int4*)(Zq + (J0+r1)*128 + c1*16);
    }
  }
  __syncthreads();
  const unsigned char* Bs = diag ? Zi : Zj;
  const int wave = tid>>6, lane = tid&63, quad = lane>>4, cl = lane&15;
  const int wrb = wave>>2, wcb = wave&3;
  const int wr = wrb*64, wc = wcb*64;
  const int half8 = (quad&1)*8;
  const int chq = quad>>1;
  f32x4 zero = {0.f,0.f,0.f,0.f};
  f32x4 acc[4][4];
  #pragma unroll
  for (int i=0;i<4;i++)
    #pragma unroll
    for (int j=0;j<4;j++) acc[i][j]=zero;
  #pragma unroll
  for (int kc=0;kc<4;kc++){
    const int ch = 2*kc + chq;
    long long a[4], b[4];
    #pragma unroll
    for (int mt=0;mt<4;mt++){
      int R = wr + mt*16 + cl;
      a[mt] = *(const long long*)&Zi[R*128 + ((ch ^ (R&7))*16) + half8];
    }
    #pragma unroll
    for (int nt=0;nt<4;nt++){
      int Cc = wc + nt*16 + cl;
      b[nt] = *(const long long*)&Bs[Cc*128 + ((ch ^ (Cc&7))*16) + half8];
    }
    #pragma unroll
    for (int mt=0;mt<4;mt++)
      #pragma unroll
      for (int nt=0;nt<4;nt++)
        acc[mt][nt] = __builtin_amdgcn_mfma_f32_16x16x32_fp8_fp8(a[mt], b[nt], acc[mt][nt], 0, 0, 0);
  }
  const float KE = 2.8853900817779268f;  // (1/TEMP)*log2(e) = 2*log2(e)
  f32x2 z2 = {0.f,0.f};
  f32x2 rs01[4] = {z2,z2,z2,z2}, rs23[4] = {z2,z2,z2,z2};
  f32x2 cs[4] = {z2,z2,z2,z2};
  #pragma unroll
  for (int mt=0;mt<4;mt++){
    #pragma unroll
    for (int nt=0;nt<4;nt++){
      f32x4 v = acc[mt][nt];
      float e0 = exp2f(v[0]*KE), e1 = exp2f(v[1]*KE);
      float e2 = exp2f(v[2]*KE), e3 = exp2f(v[3]*KE);
      f32x2 p01 = {e0,e1}, p23 = {e2,e3};
      rs01[mt] += p01; rs23[mt] += p23;
      cs[nt] += p01; cs[nt] += p23;
    }
  }
  // row-side: reduce over cl (16 lanes) within quad; quad cl==0 lane owns 4 rows
  #pragma unroll
  for (int mt=0;mt<4;mt++){
    union{f32x2 v; double d;} u0, u1;
    u0.v = rs01[mt]; u1.v = rs23[mt];
    #pragma unroll
    for (int m=1;m<16;m<<=1){
      union{double d; f32x2 v;} o0, o1;
      o0.d = __shfl_xor(u0.d, m); o1.d = __shfl_xor(u1.d, m);
      u0.v += o0.v; u1.v += o1.v;
    }
    if (cl==0){
      int R = wr + mt*16 + quad*4;
      Srow4[wcb][R+0] = u0.v.x; Srow4[wcb][R+1] = u0.v.y;
      Srow4[wcb][R+2] = u1.v.x; Srow4[wcb][R+3] = u1.v.y;
    }
  }
  // col-side: reduce over quads (16 rows each); quad0 lanes own 64 cols of this wave
  if (!diag){
    #pragma unroll
    for (int nt=0;nt<4;nt++){
      float s = cs[nt].x + cs[nt].y;
      s += __shfl_xor(s,16); s += __shfl_xor(s,32);
      if (quad==0) Scol4[wrb][wc + nt*16 + cl] = s;
    }
  }
  __syncthreads();
  if (tid < 256){
    float v = Srow4[0][tid] + Srow4[1][tid] + Srow4[2][tid] + Srow4[3][tid];
    P[((long)bi*64 + bj)*256 + tid] = v;
  } else if (tid < 512 && !diag){
    int c = tid - 256;
    float v = Scol4[0][c] + Scol4[1][c] + Scol4[2][c] + Scol4[3][c];
    P[((long)bj*64 + bi)*256 + c] = v;
  }
}

// ---- S[i] = sum_b P[i>>8][b][i&255] ----
__global__ void reduceS_k(const float* __restrict__ P, float* __restrict__ S){
  int i = blockIdx.x*256 + threadIdx.x;   // 0..16383
  int a = i >> 8, r = i & 255;
  const float* p = P + ((long)a*64)*256 + r;
  float s = 0.f;
  #pragma unroll
  for (int b=0;b<64;b++) s += p[b*256];
  S[i] = s;
}

// ---- final loss: mean_i 0.5*[(log(S[i]-E2) - 2 bdot) + (log(S[8192+i]-E2) - 2 bdot)] ----
__global__ void loss_k(const float* __restrict__ S, const float* __restrict__ bdot,
                       float* __restrict__ out){
  __shared__ float red[256];
  const float E2 = 7.3890560989306495f;  // exp(2) = diag(refl)
  int t = threadIdx.x;
  float s = 0.f;
  for (int i=t;i<NROWS;i+=256){
    float lb = 2.f * bdot[i];
    float d1 = S[i] - E2;
    float d2 = S[NROWS+i] - E2;
    s += 0.5f * ((logf(d1) - lb) + (logf(d2) - lb));
  }
  red[t]=s; __syncthreads();
  for (int st=128; st>0; st>>=1){ if (t<st) red[t]+=red[t+st]; __syncthreads(); }
  if (t==0) out[0] = red[0] / (float)NROWS;
}

extern "C" void kernel_launch(void* const* d_in, const int* in_sizes, int n_in,
                              void* d_out, int out_size, void* d_ws, size_t ws_size,
                              hipStream_t stream){
  const float* feat1 = (const float*)d_in[0];
  const float* feat2 = (const float*)d_in[1];
  const int*   ei1   = (const int*)d_in[2];
  const float* w1    = (const float*)d_in[3];
  const int*   ei2   = (const int*)d_in[4];
  const float* w2    = (const float*)d_in[5];
  const float* w_l1a = (const float*)d_in[6];
  const float* b_l1a = (const float*)d_in[7];
  const float* w_l1b = (const float*)d_in[8];
  const float* b_l1b = (const float*)d_in[9];
  const float* w_g1  = (const float*)d_in[10];
  const float* b_g1  = (const float*)d_in[11];
  const float* w_g2  = (const float*)d_in[12];
  const float* b_g2  = (const float*)d_in[13];
  const float* w_fc1 = (const float*)d_in[14];
  const float* b_fc1 = (const float*)d_in[15];
  const float* w_fc2 = (const float*)d_in[16];
  const float* b_fc2 = (const float*)d_in[17];

  char* base = (char*)d_ws;
  size_t off = 0;
  auto alloc = [&](size_t bytes)->void*{
    void* r = base + off;
    off = (off + bytes + 255) & ~(size_t)255;
    return r;
  };
  float* z    = (float*)alloc((size_t)MROWS*128*4);
  unsigned short* zq = (unsigned short*)alloc((size_t)MROWS*128);   // fp8 [16384,128]
  short* a1   = (short*)alloc((size_t)MROWS*64*2);
  short* xb   = (short*)alloc((size_t)MROWS*32*2);
  short* s1   = (short*)alloc((size_t)MROWS*256*2);
  short* hb   = (short*)alloc((size_t)MROWS*256*2);
  short* s2   = (short*)alloc((size_t)MROWS*128*2);
  short* hh   = (short*)alloc((size_t)MROWS*128*2);
  short* t2   = (short*)alloc((size_t)MROWS*64*2);
  short* wl1a_t = (short*)alloc(512*64*2);
  short* wl1b_t = (short*)alloc(64*32*2);
  short* wg1_t  = (short*)alloc(32*256*2);
  short* wg2_t  = (short*)alloc(256*128*2);
  short* wfc1_t = (short*)alloc(128*64*2);
  short* wfc2_t = (short*)alloc(64*128*2);
  float* P    = (float*)alloc((size_t)64*64*256*4);   // per-block gram partials (4MB)
  float* S    = (float*)alloc((size_t)MROWS*4);
  // contiguous zero region: deg1 deg2 (one memset)
  int*   deg1 = (int*)alloc(NROWS*4);
  int*   deg2 = (int*)alloc(NROWS*4);
  int* rs1  = (int*)alloc((NROWS+1)*4);
  int* cur1 = (int*)alloc(NROWS*4);
  int* rs2  = (int*)alloc((NROWS+1)*4);
  int* cur2 = (int*)alloc(NROWS*4);
  int*   ecol1 = (int*)alloc((size_t)NEDGE*4);
  float* ewt1  = (float*)alloc((size_t)NEDGE*4);
  int*   ecol2 = (int*)alloc((size_t)NEDGE*4);
  float* ewt2  = (float*)alloc((size_t)NEDGE*4);
  float* bdot  = (float*)alloc(NROWS*4);

  hipMemsetAsync(deg1, 0, (size_t)2*NROWS*4, stream);

  WtArgs wa;
  wa.src[0]=w_l1a; wa.dst[0]=wl1a_t; wa.K[0]=512; wa.N[0]=64;
  wa.src[1]=w_l1b; wa.dst[1]=wl1b_t; wa.K[1]=64;  wa.N[1]=32;
  wa.src[2]=w_g1;  wa.dst[2]=wg1_t;  wa.K[2]=32;  wa.N[2]=256;
  wa.src[3]=w_g2;  wa.dst[3]=wg2_t;  wa.K[3]=256; wa.N[3]=128;
  wa.src[4]=w_fc1; wa.dst[4]=wfc1_t; wa.K[4]=128; wa.N[4]=64;
  wa.src[5]=w_fc2; wa.dst[5]=wfc2_t; wa.K[5]=64;  wa.N[5]=128;
  wa.off[0]=0;
  for (int i=0;i<6;i++) wa.off[i+1] = wa.off[i] + wa.K[i]*wa.N[i];
  wtall_k<<<(wa.off[6]+255)/256,256,0,stream>>>(wa);

  hist2_k<<<2*(NEDGE/256),256,0,stream>>>(ei1, ei2, deg1, deg2);
  scan2_k<<<2,256,0,stream>>>(deg1, rs1, cur1, deg2, rs2, cur2);
  fill2_k<<<2*(NEDGE/256),256,0,stream>>>(ei1, w1, cur1, ecol1, ewt1,
                                          ei2, w2, cur2, ecol2, ewt2);

  // encoder (both graphs batched: rows 0..8191 = view1, 8192..16383 = view2)
  gemm_k<64,512,1,true,true,false><<<MROWS/64,256,0,stream>>>(feat1, feat2, wl1a_t, b_l1a, a1);
  gemm_k<32,64,0,false,true,false><<<MROWS/64,256,0,stream>>>(a1, nullptr, wl1b_t, b_l1b, xb);
  gemm_k<256,32,0,false,false,false><<<MROWS/64,256,0,stream>>>(xb, nullptr, wg1_t, nullptr, s1);
  gather_k<256,true><<<MROWS/8,256,0,stream>>>(s1, rs1,ecol1,ewt1, rs2,ecol2,ewt2, b_g1, hb);
  gemm_k<128,256,0,false,false,false><<<MROWS/64,256,0,stream>>>(hb, nullptr, wg2_t, nullptr, s2);
  gather_k<128,false><<<MROWS/16,256,0,stream>>>(s2, rs1,ecol1,ewt1, rs2,ecol2,ewt2, b_g2, hh);
  // projection
  gemm_k<64,128,2,false,true,false><<<MROWS/64,256,0,stream>>>(hh, nullptr, wfc1_t, b_fc1, t2);
  gemm_k<128,64,0,false,true,true><<<MROWS/64,256,0,stream>>>(t2, nullptr, wfc2_t, b_fc2, z);

  norm_k<<<NROWS/4,256,0,stream>>>(z, zq, bdot);

  gram2_k<<<2080,1024,0,stream>>>((const unsigned char*)zq, P);
  reduceS_k<<<MROWS/256,256,0,stream>>>(P, S);

  loss_k<<<1,256,0,stream>>>(S, bdot, (float*)d_out);
}

// Round 5
// 328.340 us; speedup vs baseline: 1.8970x; 1.0386x over previous
//
#include <hip/hip_runtime.h>
#include <hip/hip_bf16.h>
#include <math.h>

// GRACE-style graph contrastive loss, MI355X (gfx950).
// R5: LDS-free gram3_k — Zf fragment-order layout in global (pack_k), one 64x64
// tile per wave over UT(256x256 tiles), register ping-pong K-prefetch, P partials
// alias dead workspace. gather_k: 8-deep gather unroll.
// R4 post-mortem: 72KB-LDS block => ONE block/CU resident (Occ 39%), lockstep
// phases => VALU 53%/MFMA 17%. LDS "conflicts" were b64 width-cycles (benign).

#define NROWS 8192
#define MROWS 16384
#define NEDGE 262144

typedef __attribute__((ext_vector_type(8))) short bf16x8;
typedef __attribute__((ext_vector_type(4))) float f32x4;
typedef __attribute__((ext_vector_type(2))) float f32x2;
typedef long long i64;

__device__ __forceinline__ float bf2f(short s){
  union { unsigned u; float f; } cv; cv.u = ((unsigned)(unsigned short)s) << 16; return cv.f;
}
__device__ __forceinline__ short f2bf(float f){
  union { float f; unsigned u; } cv; cv.f = f;
  unsigned u = cv.u;
  unsigned r = (u + 0x7fffu + ((u >> 16) & 1u)) >> 16;  // RNE; inputs finite
  return (short)r;
}
__device__ __forceinline__ f32x4 mfma16(bf16x8 a, bf16x8 b, f32x4 c){
  return __builtin_amdgcn_mfma_f32_16x16x32_bf16(a, b, c, 0, 0, 0);
}

// ---- fp8 e4m3fn pack (RNE) ----
__device__ unsigned char f2e4m3_sw(float f){
  float a = fabsf(f);
  unsigned s = (__float_as_uint(f)>>24)&0x80u;
  if (!(a>0.f)) return (unsigned char)s;
  if (a>448.f) a=448.f;
  int e; frexpf(a,&e);
  int eff=e-1;
  unsigned code;
  if (eff<-6){
    float q=rintf(a*512.f);
    code=(unsigned)q; if(code>7)code=7;
  } else {
    float q=rintf(a*exp2f((float)(3-eff)));
    unsigned mant=(unsigned)q;
    if(mant>=16){mant=8;eff++;}
    if(eff>8) return (unsigned char)(s|0x7e);
    code=((unsigned)(eff+7)<<3)|(mant-8);
  }
  return (unsigned char)(s|code);
}
__device__ __forceinline__ unsigned short pack2fp8(float a, float b){
#if __has_builtin(__builtin_amdgcn_cvt_pk_fp8_f32)
  int v = __builtin_amdgcn_cvt_pk_fp8_f32(a, b, 0, false);
  return (unsigned short)(v & 0xffff);
#else
  return (unsigned short)((unsigned)f2e4m3_sw(a) | ((unsigned)f2e4m3_sw(b)<<8));
#endif
}

// ---- fused weight transpose + bf16 cast for all 6 weights ----
struct WtArgs {
  const float* src[6];
  short* dst[6];
  int K[6], N[6];
  int off[7];
};
__global__ void wtall_k(WtArgs a){
  int i = blockIdx.x*256 + threadIdx.x;
  if (i >= a.off[6]) return;
  int s = 0;
  #pragma unroll
  for (int j=1;j<6;j++) if (i >= a.off[j]) s=j;
  int l = i - a.off[s];
  int K=a.K[s], N=a.N[s];
  int k=l/N, n=l-k*N;
  a.dst[s][(long)n*K+k] = f2bf(a.src[s][l]);
}

// ---- generic tall-skinny MFMA GEMM: Out[M,NN] = act(A[M,KK] @ Bt[NN,KK]^T + bias) ----
template<int NN, int KK, int ACT, bool AFP32, bool BIAS, bool OUTF32>
__global__ __launch_bounds__(256) void gemm_k(const void* __restrict__ A0, const void* __restrict__ A1,
                                              const short* __restrict__ Bt, const float* __restrict__ bias,
                                              void* __restrict__ Out){
  constexpr int WM = (NN >= 64) ? 64 : 16;
  constexpr int WN = (NN >= 64) ? (NN/4) : NN;
  constexpr int MT = WM/16, NT = WN/16;
  const int tid = threadIdx.x;
  const int wave = tid >> 6, lane = tid & 63, quad = lane >> 4, cl = lane & 15;
  const int m0 = blockIdx.x * 64;
  const int wmo = (NN >= 64) ? 0 : wave*16;
  const int wno = (NN >= 64) ? wave*WN : 0;

  f32x4 zero = {0.f,0.f,0.f,0.f};
  f32x4 acc[MT][NT];
  #pragma unroll
  for (int i=0;i<MT;i++)
    #pragma unroll
    for (int j=0;j<NT;j++) acc[i][j] = zero;

  #pragma unroll
  for (int kc = 0; kc < KK/32; kc++){
    const int ko = kc*32 + quad*8;
    bf16x8 a[MT], b[NT];
    #pragma unroll
    for (int mt=0; mt<MT; mt++){
      int row = m0 + wmo + mt*16 + cl;
      if constexpr (AFP32){
        const float* ar = (row < NROWS) ? ((const float*)A0 + (long)row*KK + ko)
                                        : ((const float*)A1 + (long)(row-NROWS)*KK + ko);
        float4 f0 = *(const float4*)ar;
        float4 f1 = *(const float4*)(ar+4);
        bf16x8 t;
        t[0]=f2bf(f0.x); t[1]=f2bf(f0.y); t[2]=f2bf(f0.z); t[3]=f2bf(f0.w);
        t[4]=f2bf(f1.x); t[5]=f2bf(f1.y); t[6]=f2bf(f1.z); t[7]=f2bf(f1.w);
        a[mt]=t;
      } else {
        a[mt] = *(const bf16x8*)((const short*)A0 + (long)row*KK + ko);
      }
    }
    #pragma unroll
    for (int nt=0; nt<NT; nt++)
      b[nt] = *(const bf16x8*)(Bt + (long)(wno + nt*16 + cl)*KK + ko);
    #pragma unroll
    for (int mt=0; mt<MT; mt++)
      #pragma unroll
      for (int nt=0; nt<NT; nt++)
        acc[mt][nt] = mfma16(a[mt], b[nt], acc[mt][nt]);
  }
  #pragma unroll
  for (int mt=0; mt<MT; mt++){
    #pragma unroll
    for (int nt=0; nt<NT; nt++){
      int col = wno + nt*16 + cl;
      float bv = 0.f;
      if constexpr (BIAS) bv = bias[col];
      #pragma unroll
      for (int r=0;r<4;r++){
        int row = m0 + wmo + mt*16 + quad*4 + r;
        float v = acc[mt][nt][r] + bv;
        if (ACT==1) v = fmaxf(v, 0.f);
        if (ACT==2) v = (v > 0.f) ? v : expm1f(v);
        if constexpr (OUTF32) ((float*)Out)[(long)row*NN + col] = v;
        else ((short*)Out)[(long)row*NN + col] = f2bf(v);
      }
    }
  }
}

// ---- CSR build (both graphs fused per kernel) ----
__global__ void hist2_k(const int* __restrict__ ei1, const int* __restrict__ ei2,
                        int* __restrict__ deg1, int* __restrict__ deg2){
  int b = blockIdx.x;
  const int* ei = (b < NEDGE/256) ? ei1 : ei2;
  int* deg = (b < NEDGE/256) ? deg1 : deg2;
  int e = (b % (NEDGE/256))*256 + threadIdx.x;
  atomicAdd(&deg[ei[e]], 1);
}
__global__ void scan2_k(const int* __restrict__ deg1, int* __restrict__ rs1, int* __restrict__ cur1,
                        const int* __restrict__ deg2, int* __restrict__ rs2, int* __restrict__ cur2){
  const int* deg = blockIdx.x ? deg2 : deg1;
  int* rowstart = blockIdx.x ? rs2 : rs1;
  int* cursor = blockIdx.x ? cur2 : cur1;
  __shared__ int csum[256];
  __shared__ int base[257];
  int t = threadIdx.x;
  int loc[32];
  int s = 0;
  for (int j=0;j<32;j++){ int d = deg[t*32+j]; loc[j] = s; s += d; }
  csum[t] = s;
  __syncthreads();
  if (t==0){ int a=0; for (int i=0;i<256;i++){ base[i]=a; a+=csum[i]; } base[256]=a; }
  __syncthreads();
  for (int j=0;j<32;j++){ int v = base[t] + loc[j]; rowstart[t*32+j]=v; cursor[t*32+j]=v; }
  if (t==0) rowstart[NROWS] = base[256];
}
__global__ void fill2_k(const int* __restrict__ ei1, const float* __restrict__ w1, int* __restrict__ cur1,
                        int* __restrict__ ecol1, float* __restrict__ ew1,
                        const int* __restrict__ ei2, const float* __restrict__ w2, int* __restrict__ cur2,
                        int* __restrict__ ecol2, float* __restrict__ ew2){
  int b = blockIdx.x;
  bool g2 = (b >= NEDGE/256);
  const int* ei = g2 ? ei2 : ei1;
  const float* w = g2 ? w2 : w1;
  int* cursor = g2 ? cur2 : cur1;
  int* ecol = g2 ? ecol2 : ecol1;
  float* ew = g2 ? ew2 : ew1;
  int e = (b % (NEDGE/256))*256 + threadIdx.x;
  int r = ei[e];
  int p = atomicAdd(&cursor[r], 1);
  ecol[p] = ei[NEDGE + e];
  ew[p] = w[e];
}

// ---- GCN aggregation (gather form), latency-optimized: 8 gathers in flight ----
__device__ __forceinline__ void acc8(float* acc, int4 v, float f){
  const unsigned* u = (const unsigned*)&v;
  #pragma unroll
  for (int i=0;i<4;i++){
    union{unsigned x; float y;} lo, hi;
    lo.x = u[i] << 16;
    hi.x = u[i] & 0xffff0000u;
    acc[2*i]   = fmaf(f, lo.y, acc[2*i]);
    acc[2*i+1] = fmaf(f, hi.y, acc[2*i+1]);
  }
}

template<int C, bool RELU>
__global__ __launch_bounds__(256) void gather_k(const short* __restrict__ sup,
    const int* __restrict__ rs1, const int* __restrict__ ec1, const float* __restrict__ w1,
    const int* __restrict__ rs2, const int* __restrict__ ec2, const float* __restrict__ w2,
    const float* __restrict__ bias, short* __restrict__ out){
  constexpr int G = C/8;
  const int g = threadIdx.x % G;
  const int sub = threadIdx.x / G;
  const int row = blockIdx.x*(256/G) + sub;
  const int* rs; const int* ec; const float* w; int soff, lr;
  if (row < NROWS){ rs=rs1; ec=ec1; w=w1; soff=0; lr=row; }
  else            { rs=rs2; ec=ec2; w=w2; soff=NROWS; lr=row-NROWS; }
  const short* sb = sup + (long)soff*C + g*8;
  float acc[8];
  #pragma unroll
  for (int j=0;j<8;j++) acc[j] = bias[g*8+j];
  const int s = rs[lr], e = rs[lr+1];
  int k = s;
  for (; k+8 <= e; k+=8){
    int c0=ec[k],c1=ec[k+1],c2=ec[k+2],c3=ec[k+3],c4=ec[k+4],c5=ec[k+5],c6=ec[k+6],c7=ec[k+7];
    float f0=w[k],f1=w[k+1],f2=w[k+2],f3=w[k+3],f4=w[k+4],f5=w[k+5],f6=w[k+6],f7=w[k+7];
    int4 v0 = *(const int4*)(sb + (long)c0*C);
    int4 v1 = *(const int4*)(sb + (long)c1*C);
    int4 v2 = *(const int4*)(sb + (long)c2*C);
    int4 v3 = *(const int4*)(sb + (long)c3*C);
    int4 v4 = *(const int4*)(sb + (long)c4*C);
    int4 v5 = *(const int4*)(sb + (long)c5*C);
    int4 v6 = *(const int4*)(sb + (long)c6*C);
    int4 v7 = *(const int4*)(sb + (long)c7*C);
    acc8(acc,v0,f0); acc8(acc,v1,f1); acc8(acc,v2,f2); acc8(acc,v3,f3);
    acc8(acc,v4,f4); acc8(acc,v5,f5); acc8(acc,v6,f6); acc8(acc,v7,f7);
  }
  for (; k+4 <= e; k+=4){
    int c0=ec[k],c1=ec[k+1],c2=ec[k+2],c3=ec[k+3];
    float f0=w[k],f1=w[k+1],f2=w[k+2],f3=w[k+3];
    int4 v0 = *(const int4*)(sb + (long)c0*C);
    int4 v1 = *(const int4*)(sb + (long)c1*C);
    int4 v2 = *(const int4*)(sb + (long)c2*C);
    int4 v3 = *(const int4*)(sb + (long)c3*C);
    acc8(acc,v0,f0); acc8(acc,v1,f1); acc8(acc,v2,f2); acc8(acc,v3,f3);
  }
  for (; k < e; k++){
    int c0=ec[k]; float f0=w[k];
    int4 v0 = *(const int4*)(sb + (long)c0*C);
    acc8(acc,v0,f0);
  }
  int4 ov;
  unsigned* ou = (unsigned*)&ov;
  #pragma unroll
  for (int i=0;i<4;i++){
    float a0 = acc[2*i], a1 = acc[2*i+1];
    if (RELU){ a0 = fmaxf(a0,0.f); a1 = fmaxf(a1,0.f); }
    unsigned p0 = (unsigned)(unsigned short)f2bf(a0);
    unsigned p1 = (unsigned)(unsigned short)f2bf(a1);
    ou[i] = p0 | (p1<<16);
  }
  *(int4*)(out + (long)row*C + g*8) = ov;
}

// ---- normalize rows of z (fp32 [16384,128]) -> fp8 zq; bdot[i] = z1n_i . z2n_i (fp32) ----
__global__ __launch_bounds__(256) void norm_k(const float* __restrict__ z, unsigned short* __restrict__ zq,
                                              float* __restrict__ bdot){
  int wave = threadIdx.x>>6, lane = threadIdx.x&63;
  int i = blockIdx.x*4 + wave;   // row pair (i, i+8192)
  float2 a2 = *(const float2*)(z + (long)i*128 + lane*2);
  float2 b2 = *(const float2*)(z + (long)(i+NROWS)*128 + lane*2);
  float sa = a2.x*a2.x + a2.y*a2.y;
  float sb = b2.x*b2.x + b2.y*b2.y;
  #pragma unroll
  for (int m=1;m<64;m<<=1){ sa += __shfl_xor(sa,m); sb += __shfl_xor(sb,m); }
  float ra = 1.f / fmaxf(sqrtf(sa), 1e-12f);
  float rb = 1.f / fmaxf(sqrtf(sb), 1e-12f);
  zq[(long)i*64 + lane]         = pack2fp8(a2.x*ra, a2.y*ra);
  zq[(long)(i+NROWS)*64 + lane] = pack2fp8(b2.x*rb, b2.y*rb);
  float d = (a2.x*ra)*(b2.x*rb) + (a2.y*ra)*(b2.y*rb);
  #pragma unroll
  for (int m=1;m<64;m<<=1) d += __shfl_xor(d,m);
  if (lane==0) bdot[i] = d;
}

// ---- repack zq (row-major fp8 [16384,128]) into MFMA A/B-fragment order ----
// Zf dword index o = rg*512 + kc*128 + lane*2 + j4 ; src dword = (rg*16+m)*32 + kc*8 + q*2 + j4
// where m=lane&15, q=lane>>4 (mfma_f32_16x16x32_fp8 fragment: lane=m+16*(k>>3), byte=k&7).
__global__ void pack_k(const unsigned* __restrict__ zq, unsigned* __restrict__ Zf){
  int o = blockIdx.x*256 + threadIdx.x;       // 0..524287
  int j4 = o & 1;
  int lane = (o>>1) & 63;
  int kc = (o>>7) & 3;
  int rg = o >> 9;
  int m = lane & 15, q = lane >> 4;
  Zf[o] = zq[(rg*16 + m)*32 + kc*8 + q*2 + j4];
}

// ---- LDS-free symmetric exp-Gram partials. One 64x64 tile per WAVE over the upper
// triangle of the 256x256 tile grid (32896 tiles). Fragments loaded straight from Zf
// (coalesced 512B dwordx2, L2-resident). Block = 4 independent waves, 2KB LDS staging.
__global__ __launch_bounds__(256,4) void gram3_k(const unsigned char* __restrict__ Zf,
                                                 float* __restrict__ P){
  __shared__ float srow[4][64];
  __shared__ float scol[4][64];
  const int wave = threadIdx.x>>6, lane = threadIdx.x&63;
  const int t = blockIdx.x*4 + wave;           // UT tile index, T=256
  // decode ti<=tj: band ti starts at ti*256 - ti*(ti-1)/2
  int ti = (int)((513.0f - sqrtf(513.0f*513.0f - 8.0f*(float)t))*0.5f);
  while ((ti+1)*256 - ((ti+1)*ti)/2 <= t) ti++;
  while (ti*256 - (ti*(ti-1))/2 > t) ti--;
  const int tj = ti + (t - (ti*256 - (ti*(ti-1))/2));
  const unsigned char* za = Zf + (long)ti*16*512 + lane*8;
  const unsigned char* zb = Zf + (long)tj*16*512 + lane*8;

  f32x4 zero = {0.f,0.f,0.f,0.f};
  f32x4 acc[4][4];
  #pragma unroll
  for (int i=0;i<4;i++)
    #pragma unroll
    for (int j=0;j<4;j++) acc[i][j]=zero;

  i64 aA[4], bA[4], aB[4], bB[4];
  #pragma unroll
  for (int x=0;x<4;x++){
    aA[x] = *(const i64*)(za + (x*4+0)*512);
    bA[x] = *(const i64*)(zb + (x*4+0)*512);
  }
  #pragma unroll
  for (int kc=0;kc<4;kc++){
    i64* ac = (kc&1) ? aB : aA;
    i64* bc = (kc&1) ? bB : bA;
    i64* an = (kc&1) ? aA : aB;
    i64* bn = (kc&1) ? bA : bB;
    if (kc<3){
      #pragma unroll
      for (int x=0;x<4;x++){
        an[x] = *(const i64*)(za + (x*4+kc+1)*512);
        bn[x] = *(const i64*)(zb + (x*4+kc+1)*512);
      }
    }
    #pragma unroll
    for (int mt=0;mt<4;mt++)
      #pragma unroll
      for (int nt=0;nt<4;nt++)
        acc[mt][nt] = __builtin_amdgcn_mfma_f32_16x16x32_fp8_fp8(ac[mt], bc[nt], acc[mt][nt], 0, 0, 0);
  }

  const int quad = lane>>4, cl = lane&15;
  const float KE = 2.8853900817779268f;  // (1/TEMP)*log2(e) = 2*log2(e)
  f32x2 z2 = {0.f,0.f};
  f32x2 rs01[4] = {z2,z2,z2,z2}, rs23[4] = {z2,z2,z2,z2};
  f32x2 cs[4] = {z2,z2,z2,z2};
  #pragma unroll
  for (int mt=0;mt<4;mt++){
    #pragma unroll
    for (int nt=0;nt<4;nt++){
      f32x4 v = acc[mt][nt];
      float e0 = exp2f(v[0]*KE), e1 = exp2f(v[1]*KE);
      float e2 = exp2f(v[2]*KE), e3 = exp2f(v[3]*KE);
      f32x2 p01 = {e0,e1}, p23 = {e2,e3};
      rs01[mt] += p01; rs23[mt] += p23;
      cs[nt] += p01; cs[nt] += p23;
    }
  }
  // row partials: reduce over cl (16 lanes); cl==0 lane of each quad holds 4 rows
  #pragma unroll
  for (int mt=0;mt<4;mt++){
    union{f32x2 v; double d;} u0, u1;
    u0.v = rs01[mt]; u1.v = rs23[mt];
    #pragma unroll
    for (int m=1;m<16;m<<=1){
      union{double d; f32x2 v;} o0, o1;
      o0.d = __shfl_xor(u0.d, m); o1.d = __shfl_xor(u1.d, m);
      u0.v += o0.v; u1.v += o1.v;
    }
    if (cl==0){
      f32x4 rv = {u0.v.x, u0.v.y, u1.v.x, u1.v.y};
      *(f32x4*)&srow[wave][mt*16 + quad*4] = rv;
    }
  }
  __threadfence_block();
  P[((long)ti*256 + tj)*64 + lane] = srow[wave][lane];
  // col partials (mirror) for off-diagonal tiles: reduce over quads
  if (ti != tj){
    #pragma unroll
    for (int nt=0;nt<4;nt++){
      float s = cs[nt].x + cs[nt].y;
      s += __shfl_xor(s,16); s += __shfl_xor(s,32);
      if (quad==0) scol[wave][nt*16 + cl] = s;
    }
    __threadfence_block();
    P[((long)tj*256 + ti)*64 + lane] = scol[wave][lane];
  }
}

// ---- S[i] = sum_b P[i>>6][b][i&63] ----
__global__ void reduceS_k(const float* __restrict__ P, float* __restrict__ S){
  int i = blockIdx.x*256 + threadIdx.x;   // 0..16383
  int a = i >> 6, r = i & 63;
  const float* p = P + (long)a*256*64 + r;
  float s = 0.f;
  #pragma unroll 8
  for (int b=0;b<256;b++) s += p[b*64];
  S[i] = s;
}

// ---- final loss: mean_i 0.5*[(log(S[i]-E2) - 2 bdot) + (log(S[8192+i]-E2) - 2 bdot)] ----
__global__ void loss_k(const float* __restrict__ S, const float* __restrict__ bdot,
                       float* __restrict__ out){
  __shared__ float red[256];
  const float E2 = 7.3890560989306495f;  // exp(2) = diag(refl)
  int t = threadIdx.x;
  float s = 0.f;
  for (int i=t;i<NROWS;i+=256){
    float lb = 2.f * bdot[i];
    float d1 = S[i] - E2;
    float d2 = S[NROWS+i] - E2;
    s += 0.5f * ((logf(d1) - lb) + (logf(d2) - lb));
  }
  red[t]=s; __syncthreads();
  for (int st=128; st>0; st>>=1){ if (t<st) red[t]+=red[t+st]; __syncthreads(); }
  if (t==0) out[0] = red[0] / (float)NROWS;
}

extern "C" void kernel_launch(void* const* d_in, const int* in_sizes, int n_in,
                              void* d_out, int out_size, void* d_ws, size_t ws_size,
                              hipStream_t stream){
  const float* feat1 = (const float*)d_in[0];
  const float* feat2 = (const float*)d_in[1];
  const int*   ei1   = (const int*)d_in[2];
  const float* w1    = (const float*)d_in[3];
  const int*   ei2   = (const int*)d_in[4];
  const float* w2    = (const float*)d_in[5];
  const float* w_l1a = (const float*)d_in[6];
  const float* b_l1a = (const float*)d_in[7];
  const float* w_l1b = (const float*)d_in[8];
  const float* b_l1b = (const float*)d_in[9];
  const float* w_g1  = (const float*)d_in[10];
  const float* b_g1  = (const float*)d_in[11];
  const float* w_g2  = (const float*)d_in[12];
  const float* b_g2  = (const float*)d_in[13];
  const float* w_fc1 = (const float*)d_in[14];
  const float* b_fc1 = (const float*)d_in[15];
  const float* w_fc2 = (const float*)d_in[16];
  const float* b_fc2 = (const float*)d_in[17];

  char* base = (char*)d_ws;
  size_t off = 0;
  auto alloc = [&](size_t bytes)->void*{
    void* r = base + off;
    off = (off + bytes + 255) & ~(size_t)255;
    return r;
  };
  // NOTE liveness aliasing: P (16MB) reuses [0,16MB) = z+zq+a1+xb+part of s1,
  // all dead by the time gram3_k runs (z after norm_k, zq after pack_k,
  // a1/xb/s1 after their consumers). Zf/bdot/S/CSR live past that point and are
  // allocated beyond 21MB.
  float* z    = (float*)alloc((size_t)MROWS*128*4);                 // [0,8M)
  unsigned short* zq = (unsigned short*)alloc((size_t)MROWS*128);   // [8M,10M) fp8
  short* a1   = (short*)alloc((size_t)MROWS*64*2);                  // [10M,12M)
  short* xb   = (short*)alloc((size_t)MROWS*32*2);                  // [12M,13M)
  short* s1   = (short*)alloc((size_t)MROWS*256*2);                 // [13M,21M)
  short* hb   = (short*)alloc((size_t)MROWS*256*2);
  short* s2   = (short*)alloc((size_t)MROWS*128*2);
  short* hh   = (short*)alloc((size_t)MROWS*128*2);
  short* t2   = (short*)alloc((size_t)MROWS*64*2);
  short* wl1a_t = (short*)alloc(512*64*2);
  short* wl1b_t = (short*)alloc(64*32*2);
  short* wg1_t  = (short*)alloc(32*256*2);
  short* wg2_t  = (short*)alloc(256*128*2);
  short* wfc1_t = (short*)alloc(128*64*2);
  short* wfc2_t = (short*)alloc(64*128*2);
  unsigned char* Zf = (unsigned char*)alloc((size_t)MROWS*128);     // fragment-order fp8
  float* S    = (float*)alloc((size_t)MROWS*4);
  // contiguous zero region: deg1 deg2 (one memset)
  int*   deg1 = (int*)alloc(NROWS*4);
  int*   deg2 = (int*)alloc(NROWS*4);
  int* rs1  = (int*)alloc((NROWS+1)*4);
  int* cur1 = (int*)alloc(NROWS*4);
  int* rs2  = (int*)alloc((NROWS+1)*4);
  int* cur2 = (int*)alloc(NROWS*4);
  int*   ecol1 = (int*)alloc((size_t)NEDGE*4);
  float* ewt1  = (float*)alloc((size_t)NEDGE*4);
  int*   ecol2 = (int*)alloc((size_t)NEDGE*4);
  float* ewt2  = (float*)alloc((size_t)NEDGE*4);
  float* bdot  = (float*)alloc(NROWS*4);
  float* P = (float*)d_ws;   // 16MB alias over dead buffers (see note above)

  hipMemsetAsync(deg1, 0, (size_t)2*NROWS*4, stream);

  WtArgs wa;
  wa.src[0]=w_l1a; wa.dst[0]=wl1a_t; wa.K[0]=512; wa.N[0]=64;
  wa.src[1]=w_l1b; wa.dst[1]=wl1b_t; wa.K[1]=64;  wa.N[1]=32;
  wa.src[2]=w_g1;  wa.dst[2]=wg1_t;  wa.K[2]=32;  wa.N[2]=256;
  wa.src[3]=w_g2;  wa.dst[3]=wg2_t;  wa.K[3]=256; wa.N[3]=128;
  wa.src[4]=w_fc1; wa.dst[4]=wfc1_t; wa.K[4]=128; wa.N[4]=64;
  wa.src[5]=w_fc2; wa.dst[5]=wfc2_t; wa.K[5]=64;  wa.N[5]=128;
  wa.off[0]=0;
  for (int i=0;i<6;i++) wa.off[i+1] = wa.off[i] + wa.K[i]*wa.N[i];
  wtall_k<<<(wa.off[6]+255)/256,256,0,stream>>>(wa);

  hist2_k<<<2*(NEDGE/256),256,0,stream>>>(ei1, ei2, deg1, deg2);
  scan2_k<<<2,256,0,stream>>>(deg1, rs1, cur1, deg2, rs2, cur2);
  fill2_k<<<2*(NEDGE/256),256,0,stream>>>(ei1, w1, cur1, ecol1, ewt1,
                                          ei2, w2, cur2, ecol2, ewt2);

  // encoder (both graphs batched: rows 0..8191 = view1, 8192..16383 = view2)
  gemm_k<64,512,1,true,true,false><<<MROWS/64,256,0,stream>>>(feat1, feat2, wl1a_t, b_l1a, a1);
  gemm_k<32,64,0,false,true,false><<<MROWS/64,256,0,stream>>>(a1, nullptr, wl1b_t, b_l1b, xb);
  gemm_k<256,32,0,false,false,false><<<MROWS/64,256,0,stream>>>(xb, nullptr, wg1_t, nullptr, s1);
  gather_k<256,true><<<MROWS/8,256,0,stream>>>(s1, rs1,ecol1,ewt1, rs2,ecol2,ewt2, b_g1, hb);
  gemm_k<128,256,0,false,false,false><<<MROWS/64,256,0,stream>>>(hb, nullptr, wg2_t, nullptr, s2);
  gather_k<128,false><<<MROWS/16,256,0,stream>>>(s2, rs1,ecol1,ewt1, rs2,ecol2,ewt2, b_g2, hh);
  // projection
  gemm_k<64,128,2,false,true,false><<<MROWS/64,256,0,stream>>>(hh, nullptr, wfc1_t, b_fc1, t2);
  gemm_k<128,64,0,false,true,true><<<MROWS/64,256,0,stream>>>(t2, nullptr, wfc2_t, b_fc2, z);

  norm_k<<<NROWS/4,256,0,stream>>>(z, zq, bdot);
  pack_k<<<MROWS*128/4/256,256,0,stream>>>((const unsigned*)zq, (unsigned*)Zf);

  gram3_k<<<8224,256,0,stream>>>(Zf, P);     // 32896 UT tiles, 4 waves/block
  reduceS_k<<<MROWS/256,256,0,stream>>>(P, S);

  loss_k<<<1,256,0,stream>>>(S, bdot, (float*)d_out);
}

// Round 6
// 300.292 us; speedup vs baseline: 2.0741x; 1.0934x over previous
//
#include <hip/hip_runtime.h>
#include <hip/hip_bf16.h>
#include <math.h>

// GRACE-style graph contrastive loss, MI355X (gfx950).
// R6: layer-1 aggregation moved BEFORE the GEMM (adj@(x@W) == (adj@x)@W, x is
// 32-wide -> gather traffic 268MB -> 33.5MB, L2-resident); norm_k writes Zf
// fragment layout directly (pack_k removed); wtall+hist fused; loss_k parallel
// (32 blocks + atomicAdd, d_out pre-zeroed); gram3 exp via raw v_exp_f32.
// R5 post-mortem: non-gram pipeline is ~268us (hidden below top-5); gather<256>
// was the largest single term by traffic arithmetic.

#define NROWS 8192
#define MROWS 16384
#define NEDGE 262144

typedef __attribute__((ext_vector_type(8))) short bf16x8;
typedef __attribute__((ext_vector_type(4))) float f32x4;
typedef __attribute__((ext_vector_type(2))) float f32x2;
typedef long long i64;

__device__ __forceinline__ float bf2f(short s){
  union { unsigned u; float f; } cv; cv.u = ((unsigned)(unsigned short)s) << 16; return cv.f;
}
__device__ __forceinline__ short f2bf(float f){
  union { float f; unsigned u; } cv; cv.f = f;
  unsigned u = cv.u;
  unsigned r = (u + 0x7fffu + ((u >> 16) & 1u)) >> 16;  // RNE; inputs finite
  return (short)r;
}
__device__ __forceinline__ f32x4 mfma16(bf16x8 a, bf16x8 b, f32x4 c){
  return __builtin_amdgcn_mfma_f32_16x16x32_bf16(a, b, c, 0, 0, 0);
}
__device__ __forceinline__ float fexp2(float x){
#if __has_builtin(__builtin_amdgcn_exp2f)
  return __builtin_amdgcn_exp2f(x);   // raw v_exp_f32; args bounded |x|<3
#else
  return exp2f(x);
#endif
}

// ---- fp8 e4m3fn pack (RNE) ----
__device__ unsigned char f2e4m3_sw(float f){
  float a = fabsf(f);
  unsigned s = (__float_as_uint(f)>>24)&0x80u;
  if (!(a>0.f)) return (unsigned char)s;
  if (a>448.f) a=448.f;
  int e; frexpf(a,&e);
  int eff=e-1;
  unsigned code;
  if (eff<-6){
    float q=rintf(a*512.f);
    code=(unsigned)q; if(code>7)code=7;
  } else {
    float q=rintf(a*exp2f((float)(3-eff)));
    unsigned mant=(unsigned)q;
    if(mant>=16){mant=8;eff++;}
    if(eff>8) return (unsigned char)(s|0x7e);
    code=((unsigned)(eff+7)<<3)|(mant-8);
  }
  return (unsigned char)(s|code);
}
__device__ __forceinline__ unsigned short pack2fp8(float a, float b){
#if __has_builtin(__builtin_amdgcn_cvt_pk_fp8_f32)
  int v = __builtin_amdgcn_cvt_pk_fp8_f32(a, b, 0, false);
  return (unsigned short)(v & 0xffff);
#else
  return (unsigned short)((unsigned)f2e4m3_sw(a) | ((unsigned)f2e4m3_sw(b)<<8));
#endif
}

// ---- fused setup: weight transpose+bf16 (first nwt blocks) + degree histogram ----
struct WtArgs {
  const float* src[6];
  short* dst[6];
  int K[6], N[6];
  int off[7];
  int nwt;
};
__global__ void setup_k(WtArgs a, const int* __restrict__ ei1, const int* __restrict__ ei2,
                        int* __restrict__ deg1, int* __restrict__ deg2){
  int b = blockIdx.x;
  if (b < a.nwt){
    int i = b*256 + threadIdx.x;
    if (i >= a.off[6]) return;
    int s = 0;
    #pragma unroll
    for (int j=1;j<6;j++) if (i >= a.off[j]) s=j;
    int l = i - a.off[s];
    int K=a.K[s], N=a.N[s];
    int k=l/N, n=l-k*N;
    a.dst[s][(long)n*K+k] = f2bf(a.src[s][l]);
  } else {
    int hb = b - a.nwt;
    const int* ei = (hb < NEDGE/256) ? ei1 : ei2;
    int* deg = (hb < NEDGE/256) ? deg1 : deg2;
    int e = (hb % (NEDGE/256))*256 + threadIdx.x;
    atomicAdd(&deg[ei[e]], 1);
  }
}

// ---- generic tall-skinny MFMA GEMM: Out[M,NN] = act(A[M,KK] @ Bt[NN,KK]^T + bias) ----
template<int NN, int KK, int ACT, bool AFP32, bool BIAS, bool OUTF32>
__global__ __launch_bounds__(256) void gemm_k(const void* __restrict__ A0, const void* __restrict__ A1,
                                              const short* __restrict__ Bt, const float* __restrict__ bias,
                                              void* __restrict__ Out){
  constexpr int WM = (NN >= 64) ? 64 : 16;
  constexpr int WN = (NN >= 64) ? (NN/4) : NN;
  constexpr int MT = WM/16, NT = WN/16;
  const int tid = threadIdx.x;
  const int wave = tid >> 6, lane = tid & 63, quad = lane >> 4, cl = lane & 15;
  const int m0 = blockIdx.x * 64;
  const int wmo = (NN >= 64) ? 0 : wave*16;
  const int wno = (NN >= 64) ? wave*WN : 0;

  f32x4 zero = {0.f,0.f,0.f,0.f};
  f32x4 acc[MT][NT];
  #pragma unroll
  for (int i=0;i<MT;i++)
    #pragma unroll
    for (int j=0;j<NT;j++) acc[i][j] = zero;

  #pragma unroll
  for (int kc = 0; kc < KK/32; kc++){
    const int ko = kc*32 + quad*8;
    bf16x8 a[MT], b[NT];
    #pragma unroll
    for (int mt=0; mt<MT; mt++){
      int row = m0 + wmo + mt*16 + cl;
      if constexpr (AFP32){
        const float* ar = (row < NROWS) ? ((const float*)A0 + (long)row*KK + ko)
                                        : ((const float*)A1 + (long)(row-NROWS)*KK + ko);
        float4 f0 = *(const float4*)ar;
        float4 f1 = *(const float4*)(ar+4);
        bf16x8 t;
        t[0]=f2bf(f0.x); t[1]=f2bf(f0.y); t[2]=f2bf(f0.z); t[3]=f2bf(f0.w);
        t[4]=f2bf(f1.x); t[5]=f2bf(f1.y); t[6]=f2bf(f1.z); t[7]=f2bf(f1.w);
        a[mt]=t;
      } else {
        a[mt] = *(const bf16x8*)((const short*)A0 + (long)row*KK + ko);
      }
    }
    #pragma unroll
    for (int nt=0; nt<NT; nt++)
      b[nt] = *(const bf16x8*)(Bt + (long)(wno + nt*16 + cl)*KK + ko);
    #pragma unroll
    for (int mt=0; mt<MT; mt++)
      #pragma unroll
      for (int nt=0; nt<NT; nt++)
        acc[mt][nt] = mfma16(a[mt], b[nt], acc[mt][nt]);
  }
  #pragma unroll
  for (int mt=0; mt<MT; mt++){
    #pragma unroll
    for (int nt=0; nt<NT; nt++){
      int col = wno + nt*16 + cl;
      float bv = 0.f;
      if constexpr (BIAS) bv = bias[col];
      #pragma unroll
      for (int r=0;r<4;r++){
        int row = m0 + wmo + mt*16 + quad*4 + r;
        float v = acc[mt][nt][r] + bv;
        if (ACT==1) v = fmaxf(v, 0.f);
        if (ACT==2) v = (v > 0.f) ? v : expm1f(v);
        if constexpr (OUTF32) ((float*)Out)[(long)row*NN + col] = v;
        else ((short*)Out)[(long)row*NN + col] = f2bf(v);
      }
    }
  }
}

// ---- CSR build (both graphs fused per kernel) ----
__global__ void scan2_k(const int* __restrict__ deg1, int* __restrict__ rs1, int* __restrict__ cur1,
                        const int* __restrict__ deg2, int* __restrict__ rs2, int* __restrict__ cur2){
  const int* deg = blockIdx.x ? deg2 : deg1;
  int* rowstart = blockIdx.x ? rs2 : rs1;
  int* cursor = blockIdx.x ? cur2 : cur1;
  __shared__ int csum[256];
  __shared__ int base[257];
  int t = threadIdx.x;
  int loc[32];
  int s = 0;
  for (int j=0;j<32;j++){ int d = deg[t*32+j]; loc[j] = s; s += d; }
  csum[t] = s;
  __syncthreads();
  if (t==0){ int a=0; for (int i=0;i<256;i++){ base[i]=a; a+=csum[i]; } base[256]=a; }
  __syncthreads();
  for (int j=0;j<32;j++){ int v = base[t] + loc[j]; rowstart[t*32+j]=v; cursor[t*32+j]=v; }
  if (t==0) rowstart[NROWS] = base[256];
}
__global__ void fill2_k(const int* __restrict__ ei1, const float* __restrict__ w1, int* __restrict__ cur1,
                        int* __restrict__ ecol1, float* __restrict__ ew1,
                        const int* __restrict__ ei2, const float* __restrict__ w2, int* __restrict__ cur2,
                        int* __restrict__ ecol2, float* __restrict__ ew2){
  int b = blockIdx.x;
  bool g2 = (b >= NEDGE/256);
  const int* ei = g2 ? ei2 : ei1;
  const float* w = g2 ? w2 : w1;
  int* cursor = g2 ? cur2 : cur1;
  int* ecol = g2 ? ecol2 : ecol1;
  float* ew = g2 ? ew2 : ew1;
  int e = (b % (NEDGE/256))*256 + threadIdx.x;
  int r = ei[e];
  int p = atomicAdd(&cursor[r], 1);
  ecol[p] = ei[NEDGE + e];
  ew[p] = w[e];
}

// ---- GCN aggregation (gather form), latency-optimized: 8 gathers in flight ----
__device__ __forceinline__ void acc8(float* acc, int4 v, float f){
  const unsigned* u = (const unsigned*)&v;
  #pragma unroll
  for (int i=0;i<4;i++){
    union{unsigned x; float y;} lo, hi;
    lo.x = u[i] << 16;
    hi.x = u[i] & 0xffff0000u;
    acc[2*i]   = fmaf(f, lo.y, acc[2*i]);
    acc[2*i+1] = fmaf(f, hi.y, acc[2*i+1]);
  }
}

template<int C, bool RELU, bool HASB>
__global__ __launch_bounds__(256) void gather_k(const short* __restrict__ sup,
    const int* __restrict__ rs1, const int* __restrict__ ec1, const float* __restrict__ w1,
    const int* __restrict__ rs2, const int* __restrict__ ec2, const float* __restrict__ w2,
    const float* __restrict__ bias, short* __restrict__ out){
  constexpr int G = C/8;
  const int g = threadIdx.x % G;
  const int sub = threadIdx.x / G;
  const int row = blockIdx.x*(256/G) + sub;
  const int* rs; const int* ec; const float* w; int soff, lr;
  if (row < NROWS){ rs=rs1; ec=ec1; w=w1; soff=0; lr=row; }
  else            { rs=rs2; ec=ec2; w=w2; soff=NROWS; lr=row-NROWS; }
  const short* sb = sup + (long)soff*C + g*8;
  float acc[8];
  #pragma unroll
  for (int j=0;j<8;j++) acc[j] = HASB ? bias[g*8+j] : 0.f;
  const int s = rs[lr], e = rs[lr+1];
  int k = s;
  for (; k+8 <= e; k+=8){
    int c0=ec[k],c1=ec[k+1],c2=ec[k+2],c3=ec[k+3],c4=ec[k+4],c5=ec[k+5],c6=ec[k+6],c7=ec[k+7];
    float f0=w[k],f1=w[k+1],f2=w[k+2],f3=w[k+3],f4=w[k+4],f5=w[k+5],f6=w[k+6],f7=w[k+7];
    int4 v0 = *(const int4*)(sb + (long)c0*C);
    int4 v1 = *(const int4*)(sb + (long)c1*C);
    int4 v2 = *(const int4*)(sb + (long)c2*C);
    int4 v3 = *(const int4*)(sb + (long)c3*C);
    int4 v4 = *(const int4*)(sb + (long)c4*C);
    int4 v5 = *(const int4*)(sb + (long)c5*C);
    int4 v6 = *(const int4*)(sb + (long)c6*C);
    int4 v7 = *(const int4*)(sb + (long)c7*C);
    acc8(acc,v0,f0); acc8(acc,v1,f1); acc8(acc,v2,f2); acc8(acc,v3,f3);
    acc8(acc,v4,f4); acc8(acc,v5,f5); acc8(acc,v6,f6); acc8(acc,v7,f7);
  }
  for (; k+4 <= e; k+=4){
    int c0=ec[k],c1=ec[k+1],c2=ec[k+2],c3=ec[k+3];
    float f0=w[k],f1=w[k+1],f2=w[k+2],f3=w[k+3];
    int4 v0 = *(const int4*)(sb + (long)c0*C);
    int4 v1 = *(const int4*)(sb + (long)c1*C);
    int4 v2 = *(const int4*)(sb + (long)c2*C);
    int4 v3 = *(const int4*)(sb + (long)c3*C);
    acc8(acc,v0,f0); acc8(acc,v1,f1); acc8(acc,v2,f2); acc8(acc,v3,f3);
  }
  for (; k < e; k++){
    int c0=ec[k]; float f0=w[k];
    int4 v0 = *(const int4*)(sb + (long)c0*C);
    acc8(acc,v0,f0);
  }
  int4 ov;
  unsigned* ou = (unsigned*)&ov;
  #pragma unroll
  for (int i=0;i<4;i++){
    float a0 = acc[2*i], a1 = acc[2*i+1];
    if (RELU){ a0 = fmaxf(a0,0.f); a1 = fmaxf(a1,0.f); }
    unsigned p0 = (unsigned)(unsigned short)f2bf(a0);
    unsigned p1 = (unsigned)(unsigned short)f2bf(a1);
    ou[i] = p0 | (p1<<16);
  }
  *(int4*)(out + (long)row*C + g*8) = ov;
}

// ---- normalize rows of z (fp32 [16384,128]) -> fp8 directly in MFMA fragment
// order (Zf); bdot[i] = z1n_i . z2n_i (fp32). Fragment mapping for
// mfma_f32_16x16x32_fp8: row r, row-dword d: kc=d>>3, q=(d>>1)&3, j4=d&1;
// Zf dword = (r>>4)*512 + kc*128 + ((r&15)+16*q)*2 + j4. Lane covers half-dword.
__global__ __launch_bounds__(256) void norm_k(const float* __restrict__ z, unsigned short* __restrict__ Zf,
                                              float* __restrict__ bdot){
  int wave = threadIdx.x>>6, lane = threadIdx.x&63;
  int i = blockIdx.x*4 + wave;   // row pair (i, i+8192)
  float2 a2 = *(const float2*)(z + (long)i*128 + lane*2);
  float2 b2 = *(const float2*)(z + (long)(i+NROWS)*128 + lane*2);
  float sa = a2.x*a2.x + a2.y*a2.y;
  float sb = b2.x*b2.x + b2.y*b2.y;
  #pragma unroll
  for (int m=1;m<64;m<<=1){ sa += __shfl_xor(sa,m); sb += __shfl_xor(sb,m); }
  float ra = 1.f / fmaxf(sqrtf(sa), 1e-12f);
  float rb = 1.f / fmaxf(sqrtf(sb), 1e-12f);
  const int d = lane>>1, kc = d>>3, q = (d>>1)&3, j4 = d&1, h = lane&1;
  const int base = kc*128 + j4;
  {
    int r = i;
    long o = ((long)(r>>4)*512 + base + ((r&15)+16*q)*2)*2 + h;
    Zf[o] = pack2fp8(a2.x*ra, a2.y*ra);
  }
  {
    int r = i + NROWS;
    long o = ((long)(r>>4)*512 + base + ((r&15)+16*q)*2)*2 + h;
    Zf[o] = pack2fp8(b2.x*rb, b2.y*rb);
  }
  float dd = (a2.x*ra)*(b2.x*rb) + (a2.y*ra)*(b2.y*rb);
  #pragma unroll
  for (int m=1;m<64;m<<=1) dd += __shfl_xor(dd,m);
  if (lane==0) bdot[i] = dd;
}

// ---- LDS-free symmetric exp-Gram partials. One 64x64 tile per WAVE over the upper
// triangle of the 256x256 tile grid (32896 tiles). Fragments loaded straight from Zf
// (coalesced 512B dwordx2, L2-resident; block's 4 waves share the A region via L1).
__global__ __launch_bounds__(256,4) void gram3_k(const unsigned char* __restrict__ Zf,
                                                 float* __restrict__ P){
  __shared__ float srow[4][64];
  __shared__ float scol[4][64];
  const int wave = threadIdx.x>>6, lane = threadIdx.x&63;
  const int t = blockIdx.x*4 + wave;           // UT tile index, T=256
  int ti = (int)((513.0f - sqrtf(513.0f*513.0f - 8.0f*(float)t))*0.5f);
  while ((ti+1)*256 - ((ti+1)*ti)/2 <= t) ti++;
  while (ti*256 - (ti*(ti-1))/2 > t) ti--;
  const int tj = ti + (t - (ti*256 - (ti*(ti-1))/2));
  const unsigned char* za = Zf + (long)ti*16*512 + lane*8;
  const unsigned char* zb = Zf + (long)tj*16*512 + lane*8;

  f32x4 zero = {0.f,0.f,0.f,0.f};
  f32x4 acc[4][4];
  #pragma unroll
  for (int i=0;i<4;i++)
    #pragma unroll
    for (int j=0;j<4;j++) acc[i][j]=zero;

  i64 aA[4], bA[4], aB[4], bB[4];
  #pragma unroll
  for (int x=0;x<4;x++){
    aA[x] = *(const i64*)(za + (x*4+0)*512);
    bA[x] = *(const i64*)(zb + (x*4+0)*512);
  }
  #pragma unroll
  for (int kc=0;kc<4;kc++){
    i64* ac = (kc&1) ? aB : aA;
    i64* bc = (kc&1) ? bB : bA;
    i64* an = (kc&1) ? aA : aB;
    i64* bn = (kc&1) ? bA : bB;
    if (kc<3){
      #pragma unroll
      for (int x=0;x<4;x++){
        an[x] = *(const i64*)(za + (x*4+kc+1)*512);
        bn[x] = *(const i64*)(zb + (x*4+kc+1)*512);
      }
    }
    #pragma unroll
    for (int mt=0;mt<4;mt++)
      #pragma unroll
      for (int nt=0;nt<4;nt++)
        acc[mt][nt] = __builtin_amdgcn_mfma_f32_16x16x32_fp8_fp8(ac[mt], bc[nt], acc[mt][nt], 0, 0, 0);
  }

  const int quad = lane>>4, cl = lane&15;
  const float KE = 2.8853900817779268f;  // (1/TEMP)*log2(e) = 2*log2(e)
  f32x2 z2 = {0.f,0.f};
  f32x2 rs01[4] = {z2,z2,z2,z2}, rs23[4] = {z2,z2,z2,z2};
  f32x2 cs[4] = {z2,z2,z2,z2};
  #pragma unroll
  for (int mt=0;mt<4;mt++){
    #pragma unroll
    for (int nt=0;nt<4;nt++){
      f32x4 v = acc[mt][nt];
      float e0 = fexp2(v[0]*KE), e1 = fexp2(v[1]*KE);
      float e2 = fexp2(v[2]*KE), e3 = fexp2(v[3]*KE);
      f32x2 p01 = {e0,e1}, p23 = {e2,e3};
      rs01[mt] += p01; rs23[mt] += p23;
      cs[nt] += p01; cs[nt] += p23;
    }
  }
  #pragma unroll
  for (int mt=0;mt<4;mt++){
    union{f32x2 v; double d;} u0, u1;
    u0.v = rs01[mt]; u1.v = rs23[mt];
    #pragma unroll
    for (int m=1;m<16;m<<=1){
      union{double d; f32x2 v;} o0, o1;
      o0.d = __shfl_xor(u0.d, m); o1.d = __shfl_xor(u1.d, m);
      u0.v += o0.v; u1.v += o1.v;
    }
    if (cl==0){
      f32x4 rv = {u0.v.x, u0.v.y, u1.v.x, u1.v.y};
      *(f32x4*)&srow[wave][mt*16 + quad*4] = rv;
    }
  }
  __threadfence_block();
  P[((long)ti*256 + tj)*64 + lane] = srow[wave][lane];
  if (ti != tj){
    #pragma unroll
    for (int nt=0;nt<4;nt++){
      float s = cs[nt].x + cs[nt].y;
      s += __shfl_xor(s,16); s += __shfl_xor(s,32);
      if (quad==0) scol[wave][nt*16 + cl] = s;
    }
    __threadfence_block();
    P[((long)tj*256 + ti)*64 + lane] = scol[wave][lane];
  }
}

// ---- S[i] = sum_b P[i>>6][b][i&63] ----
__global__ void reduceS_k(const float* __restrict__ P, float* __restrict__ S){
  int i = blockIdx.x*256 + threadIdx.x;   // 0..16383
  int a = i >> 6, r = i & 63;
  const float* p = P + (long)a*256*64 + r;
  float s = 0.f;
  #pragma unroll 8
  for (int b=0;b<256;b++) s += p[b*64];
  S[i] = s;
}

// ---- final loss (parallel, atomic accumulate into pre-zeroed d_out) ----
__global__ void loss_k(const float* __restrict__ S, const float* __restrict__ bdot,
                       float* __restrict__ out){
  __shared__ float red[256];
  const float E2 = 7.3890560989306495f;  // exp(2) = diag(refl)
  int t = threadIdx.x;
  float s = 0.f;
  for (int i = blockIdx.x*256 + t; i < NROWS; i += 256*32){
    float lb = 2.f * bdot[i];
    float d1 = S[i] - E2;
    float d2 = S[NROWS+i] - E2;
    s += 0.5f * ((logf(d1) - lb) + (logf(d2) - lb));
  }
  red[t]=s; __syncthreads();
  for (int st=128; st>0; st>>=1){ if (t<st) red[t]+=red[t+st]; __syncthreads(); }
  if (t==0) atomicAdd(out, red[0] / (float)NROWS);
}

extern "C" void kernel_launch(void* const* d_in, const int* in_sizes, int n_in,
                              void* d_out, int out_size, void* d_ws, size_t ws_size,
                              hipStream_t stream){
  const float* feat1 = (const float*)d_in[0];
  const float* feat2 = (const float*)d_in[1];
  const int*   ei1   = (const int*)d_in[2];
  const float* w1    = (const float*)d_in[3];
  const int*   ei2   = (const int*)d_in[4];
  const float* w2    = (const float*)d_in[5];
  const float* w_l1a = (const float*)d_in[6];
  const float* b_l1a = (const float*)d_in[7];
  const float* w_l1b = (const float*)d_in[8];
  const float* b_l1b = (const float*)d_in[9];
  const float* w_g1  = (const float*)d_in[10];
  const float* b_g1  = (const float*)d_in[11];
  const float* w_g2  = (const float*)d_in[12];
  const float* b_g2  = (const float*)d_in[13];
  const float* w_fc1 = (const float*)d_in[14];
  const float* b_fc1 = (const float*)d_in[15];
  const float* w_fc2 = (const float*)d_in[16];
  const float* b_fc2 = (const float*)d_in[17];

  char* base = (char*)d_ws;
  size_t off = 0;
  auto alloc = [&](size_t bytes)->void*{
    void* r = base + off;
    off = (off + bytes + 255) & ~(size_t)255;
    return r;
  };
  // P (16MB) aliases [0,16MB): z, a1, xb, ax, head of hb — all dead before gram3_k
  // (z after norm, a1 after xb-gemm, xb after gather32, ax after hb-gemm, hb after s2).
  float* z    = (float*)alloc((size_t)MROWS*128*4);                 // [0,8M)
  short* a1   = (short*)alloc((size_t)MROWS*64*2);                  // [8M,10M)
  short* xb   = (short*)alloc((size_t)MROWS*32*2);                  // [10M,11M)
  short* ax   = (short*)alloc((size_t)MROWS*32*2);                  // [11M,12M)
  short* hb   = (short*)alloc((size_t)MROWS*256*2);                 // [12M,20M)
  short* s2   = (short*)alloc((size_t)MROWS*128*2);
  short* hh   = (short*)alloc((size_t)MROWS*128*2);
  short* t2   = (short*)alloc((size_t)MROWS*64*2);
  short* wl1a_t = (short*)alloc(512*64*2);
  short* wl1b_t = (short*)alloc(64*32*2);
  short* wg1_t  = (short*)alloc(32*256*2);
  short* wg2_t  = (short*)alloc(256*128*2);
  short* wfc1_t = (short*)alloc(128*64*2);
  short* wfc2_t = (short*)alloc(64*128*2);
  unsigned short* Zf = (unsigned short*)alloc((size_t)MROWS*128);   // fragment-order fp8 (2MB)
  float* S    = (float*)alloc((size_t)MROWS*4);
  int*   deg1 = (int*)alloc(NROWS*4);                               // zeroed pair
  int*   deg2 = (int*)alloc(NROWS*4);
  int* rs1  = (int*)alloc((NROWS+1)*4);
  int* cur1 = (int*)alloc(NROWS*4);
  int* rs2  = (int*)alloc((NROWS+1)*4);
  int* cur2 = (int*)alloc(NROWS*4);
  int*   ecol1 = (int*)alloc((size_t)NEDGE*4);
  float* ewt1  = (float*)alloc((size_t)NEDGE*4);
  int*   ecol2 = (int*)alloc((size_t)NEDGE*4);
  float* ewt2  = (float*)alloc((size_t)NEDGE*4);
  float* bdot  = (float*)alloc(NROWS*4);
  float* P = (float*)d_ws;   // 16MB alias (see note)

  hipMemsetAsync(deg1, 0, (size_t)2*NROWS*4, stream);
  hipMemsetAsync(d_out, 0, sizeof(float), stream);

  WtArgs wa;
  wa.src[0]=w_l1a; wa.dst[0]=wl1a_t; wa.K[0]=512; wa.N[0]=64;
  wa.src[1]=w_l1b; wa.dst[1]=wl1b_t; wa.K[1]=64;  wa.N[1]=32;
  wa.src[2]=w_g1;  wa.dst[2]=wg1_t;  wa.K[2]=32;  wa.N[2]=256;
  wa.src[3]=w_g2;  wa.dst[3]=wg2_t;  wa.K[3]=256; wa.N[3]=128;
  wa.src[4]=w_fc1; wa.dst[4]=wfc1_t; wa.K[4]=128; wa.N[4]=64;
  wa.src[5]=w_fc2; wa.dst[5]=wfc2_t; wa.K[5]=64;  wa.N[5]=128;
  wa.off[0]=0;
  for (int i=0;i<6;i++) wa.off[i+1] = wa.off[i] + wa.K[i]*wa.N[i];
  wa.nwt = (wa.off[6]+255)/256;
  setup_k<<<wa.nwt + 2*(NEDGE/256),256,0,stream>>>(wa, ei1, ei2, deg1, deg2);
  scan2_k<<<2,256,0,stream>>>(deg1, rs1, cur1, deg2, rs2, cur2);
  fill2_k<<<2*(NEDGE/256),256,0,stream>>>(ei1, w1, cur1, ecol1, ewt1,
                                          ei2, w2, cur2, ecol2, ewt2);

  // encoder (both graphs batched: rows 0..8191 = view1, 8192..16383 = view2)
  gemm_k<64,512,1,true,true,false><<<MROWS/64,256,0,stream>>>(feat1, feat2, wl1a_t, b_l1a, a1);
  gemm_k<32,64,0,false,true,false><<<MROWS/64,256,0,stream>>>(a1, nullptr, wl1b_t, b_l1b, xb);
  // layer 1: aggregate FIRST in 32-dim space (adj@(x@W) == (adj@x)@W)
  gather_k<32,false,false><<<MROWS/64,256,0,stream>>>(xb, rs1,ecol1,ewt1, rs2,ecol2,ewt2, nullptr, ax);
  gemm_k<256,32,1,false,true,false><<<MROWS/64,256,0,stream>>>(ax, nullptr, wg1_t, b_g1, hb);
  // layer 2: GEMM then aggregate (128 < 256 wide)
  gemm_k<128,256,0,false,false,false><<<MROWS/64,256,0,stream>>>(hb, nullptr, wg2_t, nullptr, s2);
  gather_k<128,false,true><<<MROWS/16,256,0,stream>>>(s2, rs1,ecol1,ewt1, rs2,ecol2,ewt2, b_g2, hh);
  // projection
  gemm_k<64,128,2,false,true,false><<<MROWS/64,256,0,stream>>>(hh, nullptr, wfc1_t, b_fc1, t2);
  gemm_k<128,64,0,false,true,true><<<MROWS/64,256,0,stream>>>(t2, nullptr, wfc2_t, b_fc2, z);

  norm_k<<<NROWS/4,256,0,stream>>>(z, Zf, bdot);

  gram3_k<<<8224,256,0,stream>>>((const unsigned char*)Zf, P);   // 32896 UT tiles
  reduceS_k<<<MROWS/256,256,0,stream>>>(P, S);

  loss_k<<<32,256,0,stream>>>(S, bdot, (float*)d_out);
}